// Round 7
// baseline (263.661 us; speedup 1.0000x reference)
//
#include <hip/hip_runtime.h>
#include <math.h>

// LiftSplatShoot constants
#define DNUM 41
#define FH 8
#define FW 22
#define CAMC 64
#define NB 8
#define NCAM 6
#define BN 48
#define NXX 200
#define NXY 200
#define KVOX 40000                // NXX*NXY (NXZ=1)
#define CAM_CH (DNUM + CAMC)      // 105
#define HW (FH * FW)              // 176
#define CAM_STRIDE (CAM_CH * HW)  // 18480
#define OUT_PER_B (CAMC * KVOX)   // 2,560,000
#define NCOL (BN * FW)            // 1056 columns
#define PIXT (NCOL * FH)          // 8448 pixels
#define NPTS (NCOL * FH * DNUM)   // 346,368 points
#define TPB  625                  // tiles per batch (40000/64)
#define NTILE (NB * TPB)          // 5000 tiles
#define TSZ 64                    // voxels per tile

// Replicates reference safe_inverse_3x3 in float32, same op order, no fma.
__device__ __forceinline__ void inv3x3(const float* __restrict__ m, float* __restrict__ o) {
  #pragma clang fp contract(off)
  float a=m[0], b=m[1], c=m[2];
  float d=m[3], e=m[4], f=m[5];
  float g=m[6], h=m[7], i=m[8];
  float A  =  e*i - f*h;
  float Bc = -(d*i - f*g);
  float Cc =  d*h - e*g;
  float Dc = -(b*i - c*h);
  float E  =  a*i - c*g;
  float F  = -(a*h - b*g);
  float G  =  b*f - c*e;
  float H  = -(a*f - c*d);
  float I  =  a*e - b*d;
  float det = fmaxf((a*A + b*Bc) + c*Cc, 1e-8f);
  o[0]=A/det;  o[1]=Dc/det; o[2]=G/det;
  o[3]=Bc/det; o[4]=E/det;  o[5]=H/det;
  o[6]=Cc/det; o[7]=F/det;  o[8]=I/det;
}

// Phase A: one 512-thread block per (bn,w) column. Wave wv = image row h.
// Emits per-point records (voxel id or -1, weight), per-tile counts, and the
// pixel-major feature transpose featT[pix*64 + c].
__global__ __launch_bounds__(512) void lss_col(const float* __restrict__ cam_out,
                                               const float* __restrict__ rots,
                                               const float* __restrict__ trans,
                                               const float* __restrict__ intrins,
                                               const float* __restrict__ post_rots,
                                               const float* __restrict__ post_trans,
                                               float* __restrict__ featT,
                                               int* __restrict__ recVox,
                                               float* __restrict__ recW,
                                               int* __restrict__ counts) {
  #pragma clang fp contract(off)
  const int blk  = blockIdx.x;        // 0 .. NCOL-1
  const int bn   = blk / FW;
  const int w    = blk % FW;
  const int b    = bn / NCAM;
  const int tid  = threadIdx.x;
  const int wv   = tid >> 6;          // wave id 0..7 == row h
  const int lane = tid & 63;

  __shared__ float sP[9], sM[9], sPT[3], sTR[3];

  if (tid == 0) {
    float P[9], IC[9], M[9];
    inv3x3(post_rots + bn*9, P);
    inv3x3(intrins + bn*9, IC);
    const float* R = rots + bn*9;
    #pragma unroll
    for (int r = 0; r < 3; r++)
      #pragma unroll
      for (int k = 0; k < 3; k++)
        M[r*3+k] = (R[r*3+0]*IC[0+k] + R[r*3+1]*IC[3+k]) + R[r*3+2]*IC[6+k];
    #pragma unroll
    for (int j = 0; j < 9; j++) { sP[j] = P[j]; sM[j] = M[j]; }
  } else if (tid >= 8 && tid < 11) {
    sPT[tid-8]  = post_trans[bn*3 + (tid-8)];
  } else if (tid >= 11 && tid < 14) {
    sTR[tid-11] = trans[bn*3 + (tid-11)];
  }

  const int colbase = bn*CAM_STRIDE + w;   // + c*HW + h*FW

  // feature transpose: thread = (h, c); coalesced 256B per row
  {
    int fh = tid >> 6, c = tid & 63;
    featT[((size_t)(blk*FH + fh))*CAMC + c] = cam_out[colbase + (DNUM + c)*HW + fh*FW];
  }
  __syncthreads();

  const float fx = (float)((double)w * (351.0 / 21.0));
  const int h = wv;

  // per-row softmax over 41 depth logits (wave64 shuffles)
  float logit = (lane < DNUM) ? cam_out[colbase + lane*HW + h*FW] : -INFINITY;
  float mx = logit;
  #pragma unroll
  for (int off = 32; off >= 1; off >>= 1) mx = fmaxf(mx, __shfl_xor(mx, off, 64));
  float e = expf(logit - mx);
  float s = e;
  #pragma unroll
  for (int off = 32; off >= 1; off >>= 1) s += __shfl_xor(s, off, 64);

  if (lane < DNUM) {
    float fy = (float)((double)h * (127.0 / 7.0));
    float fz = 4.0f + (float)lane;
    float p0 = fx - sPT[0], p1 = fy - sPT[1], p2 = fz - sPT[2];
    float q0 = (sP[0]*p0 + sP[1]*p1) + sP[2]*p2;
    float q1 = (sP[3]*p0 + sP[4]*p1) + sP[5]*p2;
    float q2 = (sP[6]*p0 + sP[7]*p1) + sP[8]*p2;
    float r0 = q0*q2, r1 = q1*q2, r2 = q2;
    float g0 = ((sM[0]*r0 + sM[1]*r1) + sM[2]*r2) + sTR[0];
    float g1 = ((sM[3]*r0 + sM[4]*r1) + sM[5]*r2) + sTR[1];
    float g2 = ((sM[6]*r0 + sM[7]*r1) + sM[8]*r2) + sTR[2];
    int ix = (int)((g0 + 50.0f) / 0.5f);
    int iy = (int)((g1 + 50.0f) / 0.5f);
    int iz = (int)((g2 + 10.0f) / 20.0f);
    bool kept = (ix >= 0) & (ix < NXX) & (iy >= 0) & (iy < NXY) & (iz == 0);
    int v  = ix*NXY + iy;
    int gv = kept ? (b*KVOX + v) : -1;
    int pt = blk*(FH*DNUM) + h*DNUM + lane;
    recVox[pt] = gv;
    recW[pt]   = e / s;
    if (kept) atomicAdd(&counts[b*TPB + (v >> 6)], 1);
  }
}

// Exclusive scan of NTILE (=5000) tile counts; single 1024-thread block.
__global__ __launch_bounds__(1024) void lss_scan(const int* __restrict__ counts,
                                                 int* __restrict__ offsets,
                                                 int* __restrict__ cursors) {
  __shared__ int wsum[16], wbase[16];
  const int tid = threadIdx.x, lane = tid & 63, wv = tid >> 6;
  int v[5], loc = 0;
  #pragma unroll
  for (int k = 0; k < 5; k++) {
    int i = tid*5 + k;
    v[k] = (i < NTILE) ? counts[i] : 0;
    loc += v[k];
  }
  // wave-inclusive scan of per-thread sums
  int x = loc;
  #pragma unroll
  for (int off = 1; off < 64; off <<= 1) {
    int y = __shfl_up(x, off, 64);
    if (lane >= off) x += y;
  }
  if (lane == 63) wsum[wv] = x;
  __syncthreads();
  if (wv == 0 && lane < 16) {
    int sv = wsum[lane];
    int xx = sv;
    #pragma unroll
    for (int off = 1; off < 16; off <<= 1) {
      int y = __shfl_up(xx, off, 64);
      if (lane >= off) xx += y;
    }
    wbase[lane] = xx - sv;   // exclusive
  }
  __syncthreads();
  int run = wbase[wv] + (x - loc);
  #pragma unroll
  for (int k = 0; k < 5; k++) {
    int i = tid*5 + k;
    if (i < NTILE) { offsets[i] = run; cursors[i] = run; }
    run += v[k];
  }
}

// Bucket kept points into per-tile lists. Entry: (pix | v_lo<<14, weight).
__global__ __launch_bounds__(256) void lss_place(const int* __restrict__ recVox,
                                                 const float* __restrict__ recW,
                                                 int* __restrict__ cursors,
                                                 int2* __restrict__ listPW) {
  const int pt = blockIdx.x*256 + threadIdx.x;   // NPTS = 1353*256 exactly
  const int gv = recVox[pt];
  if (gv < 0) return;
  const int b    = gv / KVOX;
  const int v    = gv - b*KVOX;
  const int t    = b*TPB + (v >> 6);
  const int v_lo = v & 63;
  const int slot = atomicAdd(&cursors[t], 1);
  const int blk  = pt / (FH*DNUM);
  const int r    = pt - blk*(FH*DNUM);
  const int h    = r / DNUM;
  const int pix  = blk*FH + h;
  listPW[slot] = make_int2(pix | (v_lo << 14), __float_as_int(recW[pt]));
}

// Fused gather + transpose: one 1024-thread block per 64-voxel tile.
// 16 waves consume the tile's list in parallel (lane = channel), accumulate
// into an LDS tile via ds f32 atomics, then write the tile transposed and
// fully coalesced to out — zeros for empty voxels come free (no memset).
__global__ __launch_bounds__(1024) void lss_gatherT(const int* __restrict__ offsets,
                                                    const int* __restrict__ counts,
                                                    const int2* __restrict__ listPW,
                                                    const float* __restrict__ featT,
                                                    float* __restrict__ out) {
  __shared__ float tile[TSZ][TSZ + 1];
  const int t625 = blockIdx.x;            // 0..624
  const int b    = blockIdx.y;
  const int tid  = threadIdx.x;
  const int lane = tid & 63;
  const int wv   = tid >> 6;              // 0..15

  // zero LDS tile
  for (int idx = tid; idx < TSZ*(TSZ+1); idx += 1024)
    ((float*)tile)[idx] = 0.0f;
  __syncthreads();

  const int tg = b*TPB + t625;
  const int s0 = offsets[tg];
  const int n  = counts[tg];

  for (int j = wv; j < n; j += 16) {
    const int2 ent = listPW[s0 + j];      // wave-uniform 8B load
    const int pix  = ent.x & 0x3FFF;
    const int vlo  = ent.x >> 14;
    const float wgt = __int_as_float(ent.y);
    const float f = featT[(size_t)pix*CAMC + lane];   // 256B coalesced, L2-hit
    atomicAdd(&tile[vlo][lane], wgt * f);             // LDS f32 atomic
  }
  __syncthreads();

  // transposed write: (B, C, XY), 256B coalesced per wave
  float* dstp = out + (size_t)b*OUT_PER_B + t625*TSZ + lane;
  #pragma unroll
  for (int c0 = 0; c0 < CAMC; c0 += 16) {
    int c = c0 + wv;
    dstp[(size_t)c*KVOX] = tile[lane][c];
  }
}

// ---------------- fallback (tiny ws): round-1 direct atomic path ----------------
__global__ void lss_prep(const float* __restrict__ rots,
                         const float* __restrict__ intrins,
                         const float* __restrict__ post_rots,
                         float* __restrict__ prep) {
  #pragma clang fp contract(off)
  int bn = threadIdx.x;
  if (bn >= BN) return;
  float P[9], IC[9];
  inv3x3(post_rots + bn*9, P);
  inv3x3(intrins + bn*9, IC);
  const float* R = rots + bn*9;
  float* o = prep + bn*18;
  #pragma unroll
  for (int j = 0; j < 9; j++) o[j] = P[j];
  #pragma unroll
  for (int r = 0; r < 3; r++)
    #pragma unroll
    for (int k = 0; k < 3; k++)
      o[9 + r*3 + k] = (R[r*3+0]*IC[0+k] + R[r*3+1]*IC[3+k]) + R[r*3+2]*IC[6+k];
}

__global__ __launch_bounds__(64) void lss_scatter_direct(const float* __restrict__ cam_out,
                                                         const float* __restrict__ trans,
                                                         const float* __restrict__ post_trans,
                                                         const float* __restrict__ prep,
                                                         float* __restrict__ out) {
  #pragma clang fp contract(off)
  const int blk = blockIdx.x;
  const int bn  = blk / HW;
  const int pix = blk % HW;
  const int h   = pix / FW;
  const int w   = pix % FW;
  const int b   = bn / NCAM;
  const int tid = threadIdx.x;
  __shared__ float sP[9], sM[9], sPT[3], sTR[3];
  __shared__ float sDepth[DNUM];
  __shared__ int   sVoff[DNUM];
  if (tid < 9)       sP[tid]      = prep[bn*18 + tid];
  else if (tid < 18) sM[tid-9]    = prep[bn*18 + tid];
  else if (tid < 21) sPT[tid-18]  = post_trans[bn*3 + (tid-18)];
  else if (tid < 24) sTR[tid-21]  = trans[bn*3 + (tid-21)];
  __syncthreads();
  const int base = bn*CAM_STRIDE + h*FW + w;
  float logit = (tid < DNUM) ? cam_out[base + tid*HW] : -INFINITY;
  float mx = logit;
  #pragma unroll
  for (int off = 32; off >= 1; off >>= 1) mx = fmaxf(mx, __shfl_xor(mx, off, 64));
  float e = expf(logit - mx);
  float s = e;
  #pragma unroll
  for (int off = 32; off >= 1; off >>= 1) s += __shfl_xor(s, off, 64);
  float depth = e / s;
  if (tid < DNUM) {
    float fx = (float)((double)w * (351.0 / 21.0));
    float fy = (float)((double)h * (127.0 / 7.0));
    float fz = 4.0f + (float)tid;
    float p0 = fx - sPT[0], p1 = fy - sPT[1], p2 = fz - sPT[2];
    float q0 = (sP[0]*p0 + sP[1]*p1) + sP[2]*p2;
    float q1 = (sP[3]*p0 + sP[4]*p1) + sP[5]*p2;
    float q2 = (sP[6]*p0 + sP[7]*p1) + sP[8]*p2;
    float r0 = q0*q2, r1 = q1*q2, r2 = q2;
    float g0 = ((sM[0]*r0 + sM[1]*r1) + sM[2]*r2) + sTR[0];
    float g1 = ((sM[3]*r0 + sM[4]*r1) + sM[5]*r2) + sTR[1];
    float g2 = ((sM[6]*r0 + sM[7]*r1) + sM[8]*r2) + sTR[2];
    int ix = (int)((g0 + 50.0f) / 0.5f);
    int iy = (int)((g1 + 50.0f) / 0.5f);
    int iz = (int)((g2 + 10.0f) / 20.0f);
    bool kept = (ix >= 0) & (ix < NXX) & (iy >= 0) & (iy < NXY) & (iz == 0);
    sVoff[tid]  = kept ? (ix*NXY + iy) : -1;
    sDepth[tid] = depth;
  }
  __syncthreads();
  const float feat = cam_out[base + (DNUM + tid)*HW];
  float* outb = out + (size_t)b*OUT_PER_B + (size_t)tid*KVOX;
  #pragma unroll 1
  for (int d = 0; d < DNUM; d++) {
    int v = sVoff[d];
    if (v >= 0) atomicAdd(outb + v, sDepth[d] * feat);
  }
}

extern "C" void kernel_launch(void* const* d_in, const int* in_sizes, int n_in,
                              void* d_out, int out_size, void* d_ws, size_t ws_size,
                              hipStream_t stream) {
  const float* cam_out    = (const float*)d_in[0];
  const float* rots       = (const float*)d_in[1];
  const float* trans      = (const float*)d_in[2];
  const float* intrins    = (const float*)d_in[3];
  const float* post_rots  = (const float*)d_in[4];
  const float* post_trans = (const float*)d_in[5];
  float* out = (float*)d_out;
  char*  ws  = (char*)d_ws;

  // ws layout (listPW first: 8B-aligned; featT lands 256B-aligned since
  // NPTS*8 = 2,770,944 is a multiple of 256)
  int2*  listPW  = (int2*)ws;                                   // NPTS
  float* featT   = (float*)(ws + (size_t)NPTS*8);               // PIXT*CAMC
  int*   recVox  = (int*)(featT + (size_t)PIXT*CAMC);           // NPTS
  float* recW    = (float*)(recVox + NPTS);                     // NPTS
  int*   counts  = (int*)(recW + NPTS);                         // NTILE
  int*   offsets = counts + NTILE;                              // NTILE
  int*   cursors = offsets + NTILE;                             // NTILE
  const size_t need = (size_t)((char*)(cursors + NTILE) - ws);

  if (ws_size >= need) {
    hipMemsetAsync(counts, 0, (size_t)NTILE*sizeof(int), stream);
    lss_col<<<NCOL, 512, 0, stream>>>(cam_out, rots, trans, intrins,
                                      post_rots, post_trans,
                                      featT, recVox, recW, counts);
    lss_scan<<<1, 1024, 0, stream>>>(counts, offsets, cursors);
    lss_place<<<NPTS/256, 256, 0, stream>>>(recVox, recW, cursors, listPW);
    dim3 g(TPB, NB);
    lss_gatherT<<<g, 1024, 0, stream>>>(offsets, counts, listPW, featT, out);
  } else {
    float* prep = (float*)ws;   // BN*18 floats
    hipMemsetAsync(out, 0, (size_t)out_size*sizeof(float), stream);
    lss_prep<<<1, 64, 0, stream>>>(rots, intrins, post_rots, prep);
    lss_scatter_direct<<<BN * HW, 64, 0, stream>>>(cam_out, trans, post_trans, prep, out);
  }
}

// Round 8
// 219.980 us; speedup vs baseline: 1.1986x; 1.1986x over previous
//
#include <hip/hip_runtime.h>
#include <math.h>

// LiftSplatShoot constants
#define DNUM 41
#define FH 8
#define FW 22
#define CAMC 64
#define NB 8
#define NCAM 6
#define BN 48
#define NXX 200
#define NXY 200
#define KVOX 40000                // NXX*NXY (NXZ=1)
#define CAM_CH (DNUM + CAMC)      // 105
#define HW (FH * FW)              // 176
#define CAM_STRIDE (CAM_CH * HW)  // 18480
#define OUT_PER_B (CAMC * KVOX)   // 2,560,000
#define NROW (BN * FH)            // 384 row-blocks
#define GEOM_PTS (DNUM * FW)      // 902 points per row-block
#define PIXT (BN * HW)            // 8448 pixels
#define NPTS (NROW * GEOM_PTS)    // 346,368 points
#define TPB  625                  // tiles per batch (40000/64)
#define NTILE (NB * TPB)          // 5000 tiles
#define TSZ 64                    // voxels per tile

// Replicates reference safe_inverse_3x3 in float32, same op order, no fma.
__device__ __forceinline__ void inv3x3(const float* __restrict__ m, float* __restrict__ o) {
  #pragma clang fp contract(off)
  float a=m[0], b=m[1], c=m[2];
  float d=m[3], e=m[4], f=m[5];
  float g=m[6], h=m[7], i=m[8];
  float A  =  e*i - f*h;
  float Bc = -(d*i - f*g);
  float Cc =  d*h - e*g;
  float Dc = -(b*i - c*h);
  float E  =  a*i - c*g;
  float F  = -(a*h - b*g);
  float G  =  b*f - c*e;
  float H  = -(a*f - c*d);
  float I  =  a*e - b*d;
  float det = fmaxf((a*A + b*Bc) + c*Cc, 1e-8f);
  o[0]=A/det;  o[1]=Dc/det; o[2]=G/det;
  o[3]=Bc/det; o[4]=E/det;  o[5]=H/det;
  o[6]=Cc/det; o[7]=F/det;  o[8]=I/det;
}

// Run-aggregated atomic add over a wave: maximal runs of CONTIGUOUS valid
// lanes with equal key t issue ONE atomicAdd(ctr+t, run_len) from the run
// leader. Returns base+pos (this lane's slot); undefined when !valid.
// Must be called with the whole wave converged (uniform loop bounds).
__device__ __forceinline__ int wave_run_slot(int* __restrict__ ctr, int t, bool valid) {
  const int lane = threadIdx.x & 63;
  const unsigned long long act = __ballot(valid);
  const int tprev = __shfl_up(t, 1, 64);
  const bool leader = valid && ((lane == 0) ||
                                (((act >> (lane - 1)) & 1ull) == 0) ||
                                (tprev != t));
  const unsigned long long lm = __ballot(leader);
  int base = 0, ldr = 0, pos = 0;
  if (valid) {
    unsigned long long below = lm & (~0ull >> (63 - lane));   // bits [0,lane]
    ldr = 63 - __clzll((long long)below);
    pos = lane - ldr;
  }
  if (leader) {
    unsigned long long bound = lm | ~act;                      // run boundaries
    unsigned long long above = (lane == 63) ? 0ull : (bound >> (lane + 1));
    int len = above ? __ffsll((long long)above) : (64 - lane);
    base = atomicAdd(ctr + t, len);
  }
  base = __shfl(base, ldr, 64);
  return base + pos;
}

// Phase A: one 256-thread block per (bn, h) image row. All global loads are
// coalesced runs of 22 floats (row-contiguous). Emits per-point records,
// run-aggregated tile counts, and pix-major featT (via LDS transpose).
__global__ __launch_bounds__(256) void lss_col(const float* __restrict__ cam_out,
                                               const float* __restrict__ rots,
                                               const float* __restrict__ trans,
                                               const float* __restrict__ intrins,
                                               const float* __restrict__ post_rots,
                                               const float* __restrict__ post_trans,
                                               float* __restrict__ featT,
                                               int* __restrict__ recVox,
                                               float* __restrict__ recW,
                                               int* __restrict__ counts) {
  #pragma clang fp contract(off)
  const int blk = blockIdx.x;          // 0..NROW-1 : bn*FH + h
  const int bn  = blk / FH;
  const int h   = blk % FH;
  const int b   = bn / NCAM;
  const int tid = threadIdx.x;

  __shared__ float sP[9], sM[9], sPT[3], sTR[3];
  __shared__ float Llog[DNUM][FW];     // logits, row h
  __shared__ float Lf[CAMC][FW + 1];   // features, padded
  __shared__ float sMax[FW], sSum[FW];

  if (tid == 0) {
    float P[9], IC[9], M[9];
    inv3x3(post_rots + bn*9, P);
    inv3x3(intrins + bn*9, IC);
    const float* R = rots + bn*9;
    #pragma unroll
    for (int r = 0; r < 3; r++)
      #pragma unroll
      for (int k = 0; k < 3; k++)
        M[r*3+k] = (R[r*3+0]*IC[0+k] + R[r*3+1]*IC[3+k]) + R[r*3+2]*IC[6+k];
    #pragma unroll
    for (int j = 0; j < 9; j++) { sP[j] = P[j]; sM[j] = M[j]; }
  } else if (tid >= 8 && tid < 11) {
    sPT[tid-8]  = post_trans[bn*3 + (tid-8)];
  } else if (tid >= 11 && tid < 14) {
    sTR[tid-11] = trans[bn*3 + (tid-11)];
  }

  const int rowbase = bn*CAM_STRIDE + h*FW;   // + ch*HW + w

  // stage logits (41x22) — coalesced
  for (int e = tid; e < DNUM*FW; e += 256) {
    int d = e / FW, w2 = e - (e/FW)*FW;
    Llog[d][w2] = cam_out[rowbase + d*HW + w2];
  }
  // stage features (64x22) — coalesced
  for (int e = tid; e < CAMC*FW; e += 256) {
    int c = e / FW, w2 = e - (e/FW)*FW;
    Lf[c][w2] = cam_out[rowbase + (DNUM + c)*HW + w2];
  }
  __syncthreads();

  // featT write, pix-major [pix][c] — fully coalesced 256B runs
  const int pixbase = blk * FW;
  for (int e = tid; e < CAMC*FW; e += 256) {
    int w2 = e >> 6, c = e & 63;
    featT[(size_t)(pixbase + w2)*CAMC + c] = Lf[c][w2];
  }

  // per-pixel softmax reductions (22 serial reducers; exact fmax chain)
  if (tid < FW) {
    float mx = -INFINITY;
    for (int d = 0; d < DNUM; d++) mx = fmaxf(mx, Llog[d][tid]);
    float ss = 0.0f;
    for (int d = 0; d < DNUM; d++) ss += expf(Llog[d][tid] - mx);
    sMax[tid] = mx; sSum[tid] = ss;
  }
  __syncthreads();

  // geometry + records + aggregated counts (uniform loop: full-wave ballots)
  const float fy = (float)((double)h * (127.0 / 7.0));
  const int ptbase = blk * GEOM_PTS;
  for (int e0 = 0; e0 < GEOM_PTS; e0 += 256) {
    const int e  = e0 + tid;
    const bool in = (e < GEOM_PTS);
    const int ec = in ? e : 0;
    const int d  = ec / FW;
    const int w2 = ec - d*FW;
    const float dep = expf(Llog[d][w2] - sMax[w2]) / sSum[w2];
    const float fx = (float)((double)w2 * (351.0 / 21.0));
    const float fz = 4.0f + (float)d;
    float p0 = fx - sPT[0], p1 = fy - sPT[1], p2 = fz - sPT[2];
    float q0 = (sP[0]*p0 + sP[1]*p1) + sP[2]*p2;
    float q1 = (sP[3]*p0 + sP[4]*p1) + sP[5]*p2;
    float q2 = (sP[6]*p0 + sP[7]*p1) + sP[8]*p2;
    float r0 = q0*q2, r1 = q1*q2, r2 = q2;
    float g0 = ((sM[0]*r0 + sM[1]*r1) + sM[2]*r2) + sTR[0];
    float g1 = ((sM[3]*r0 + sM[4]*r1) + sM[5]*r2) + sTR[1];
    float g2 = ((sM[6]*r0 + sM[7]*r1) + sM[8]*r2) + sTR[2];
    int ix = (int)((g0 + 50.0f) / 0.5f);
    int iy = (int)((g1 + 50.0f) / 0.5f);
    int iz = (int)((g2 + 10.0f) / 20.0f);
    bool kept = (ix >= 0) & (ix < NXX) & (iy >= 0) & (iy < NXY) & (iz == 0);
    const int v = ix*NXY + iy;
    const bool valid = in && kept;
    const int t = valid ? (b*TPB + (v >> 6)) : -1;
    wave_run_slot(counts, t, valid);                 // aggregated count
    if (in) {
      recVox[ptbase + e] = valid ? (b*KVOX + v) : -1;
      recW[ptbase + e]   = dep;
    }
  }
}

// Exclusive scan of NTILE (=5000) tile counts; single 1024-thread block.
__global__ __launch_bounds__(1024) void lss_scan(const int* __restrict__ counts,
                                                 int* __restrict__ offsets,
                                                 int* __restrict__ cursors) {
  __shared__ int wsum[16], wbase[16];
  const int tid = threadIdx.x, lane = tid & 63, wv = tid >> 6;
  int v[5], loc = 0;
  #pragma unroll
  for (int k = 0; k < 5; k++) {
    int i = tid*5 + k;
    v[k] = (i < NTILE) ? counts[i] : 0;
    loc += v[k];
  }
  int x = loc;
  #pragma unroll
  for (int off = 1; off < 64; off <<= 1) {
    int y = __shfl_up(x, off, 64);
    if (lane >= off) x += y;
  }
  if (lane == 63) wsum[wv] = x;
  __syncthreads();
  if (wv == 0 && lane < 16) {
    int sv = wsum[lane];
    int xx = sv;
    #pragma unroll
    for (int off = 1; off < 16; off <<= 1) {
      int y = __shfl_up(xx, off, 64);
      if (lane >= off) xx += y;
    }
    wbase[lane] = xx - sv;   // exclusive
  }
  __syncthreads();
  int run = wbase[wv] + (x - loc);
  #pragma unroll
  for (int k = 0; k < 5; k++) {
    int i = tid*5 + k;
    if (i < NTILE) { offsets[i] = run; cursors[i] = run; }
    run += v[k];
  }
}

// Bucket kept points into per-tile lists, run-aggregated cursor atomics.
__global__ __launch_bounds__(256) void lss_place(const int* __restrict__ recVox,
                                                 const float* __restrict__ recW,
                                                 int* __restrict__ cursors,
                                                 int2* __restrict__ listPW) {
  const int pt = blockIdx.x*256 + threadIdx.x;   // NPTS = 1353*256 exactly
  const int gv = recVox[pt];
  const bool valid = (gv >= 0);
  const int b = valid ? (gv / KVOX) : 0;
  const int v = gv - b*KVOX;
  const int t = valid ? (b*TPB + (v >> 6)) : -1;
  const int slot = wave_run_slot(cursors, t, valid);
  if (valid) {
    const int vlo = v & 63;
    const int blk = pt / GEOM_PTS;
    const int r   = pt - blk*GEOM_PTS;
    const int w2  = r - (r/FW)*FW;
    const int pix = blk*FW + w2;
    listPW[slot] = make_int2(pix | (vlo << 14), __float_as_int(recW[pt]));
  }
}

// Fused gather + transpose, 4-deep ILP. One 1024-thread block per tile.
// 16 waves x 4 entries in flight (lane = channel); LDS f32 atomics; final
// write is transposed and fully coalesced — zeros for empty voxels free.
__global__ __launch_bounds__(1024) void lss_gatherT(const int* __restrict__ offsets,
                                                    const int* __restrict__ counts,
                                                    const int2* __restrict__ listPW,
                                                    const float* __restrict__ featT,
                                                    float* __restrict__ out) {
  __shared__ float tile[TSZ][TSZ + 1];
  const int t625 = blockIdx.x;            // 0..624
  const int b    = blockIdx.y;
  const int tid  = threadIdx.x;
  const int lane = tid & 63;
  const int wv   = tid >> 6;              // 0..15

  for (int idx = tid; idx < TSZ*(TSZ+1); idx += 1024)
    ((float*)tile)[idx] = 0.0f;
  __syncthreads();

  const int tg = b*TPB + t625;
  const int s0 = offsets[tg];
  const int n  = counts[tg];

  for (int j0 = wv*4; j0 < n; j0 += 64) {
    const int rem = n - j0;
    const int2 e0 = listPW[s0 + j0];
    const int2 e1 = (rem > 1) ? listPW[s0 + j0 + 1] : make_int2(0, 0);
    const int2 e2 = (rem > 2) ? listPW[s0 + j0 + 2] : make_int2(0, 0);
    const int2 e3 = (rem > 3) ? listPW[s0 + j0 + 3] : make_int2(0, 0);
    const float f0 = featT[(size_t)(e0.x & 0x3FFF)*CAMC + lane];
    const float f1 = featT[(size_t)(e1.x & 0x3FFF)*CAMC + lane];
    const float f2 = featT[(size_t)(e2.x & 0x3FFF)*CAMC + lane];
    const float f3 = featT[(size_t)(e3.x & 0x3FFF)*CAMC + lane];
    atomicAdd(&tile[e0.x >> 14][lane], __int_as_float(e0.y) * f0);
    if (rem > 1) atomicAdd(&tile[e1.x >> 14][lane], __int_as_float(e1.y) * f1);
    if (rem > 2) atomicAdd(&tile[e2.x >> 14][lane], __int_as_float(e2.y) * f2);
    if (rem > 3) atomicAdd(&tile[e3.x >> 14][lane], __int_as_float(e3.y) * f3);
  }
  __syncthreads();

  float* dstp = out + (size_t)b*OUT_PER_B + t625*TSZ + lane;
  #pragma unroll
  for (int c0 = 0; c0 < CAMC; c0 += 16) {
    int c = c0 + wv;
    dstp[(size_t)c*KVOX] = tile[lane][c];
  }
}

// ---------------- fallback (tiny ws): round-1 direct atomic path ----------------
__global__ void lss_prep(const float* __restrict__ rots,
                         const float* __restrict__ intrins,
                         const float* __restrict__ post_rots,
                         float* __restrict__ prep) {
  #pragma clang fp contract(off)
  int bn = threadIdx.x;
  if (bn >= BN) return;
  float P[9], IC[9];
  inv3x3(post_rots + bn*9, P);
  inv3x3(intrins + bn*9, IC);
  const float* R = rots + bn*9;
  float* o = prep + bn*18;
  #pragma unroll
  for (int j = 0; j < 9; j++) o[j] = P[j];
  #pragma unroll
  for (int r = 0; r < 3; r++)
    #pragma unroll
    for (int k = 0; k < 3; k++)
      o[9 + r*3 + k] = (R[r*3+0]*IC[0+k] + R[r*3+1]*IC[3+k]) + R[r*3+2]*IC[6+k];
}

__global__ __launch_bounds__(64) void lss_scatter_direct(const float* __restrict__ cam_out,
                                                         const float* __restrict__ trans,
                                                         const float* __restrict__ post_trans,
                                                         const float* __restrict__ prep,
                                                         float* __restrict__ out) {
  #pragma clang fp contract(off)
  const int blk = blockIdx.x;
  const int bn  = blk / HW;
  const int pix = blk % HW;
  const int h   = pix / FW;
  const int w   = pix % FW;
  const int b   = bn / NCAM;
  const int tid = threadIdx.x;
  __shared__ float sP[9], sM[9], sPT[3], sTR[3];
  __shared__ float sDepth[DNUM];
  __shared__ int   sVoff[DNUM];
  if (tid < 9)       sP[tid]      = prep[bn*18 + tid];
  else if (tid < 18) sM[tid-9]    = prep[bn*18 + tid];
  else if (tid < 21) sPT[tid-18]  = post_trans[bn*3 + (tid-18)];
  else if (tid < 24) sTR[tid-21]  = trans[bn*3 + (tid-21)];
  __syncthreads();
  const int base = bn*CAM_STRIDE + h*FW + w;
  float logit = (tid < DNUM) ? cam_out[base + tid*HW] : -INFINITY;
  float mx = logit;
  #pragma unroll
  for (int off = 32; off >= 1; off >>= 1) mx = fmaxf(mx, __shfl_xor(mx, off, 64));
  float e = expf(logit - mx);
  float s = e;
  #pragma unroll
  for (int off = 32; off >= 1; off >>= 1) s += __shfl_xor(s, off, 64);
  float depth = e / s;
  if (tid < DNUM) {
    float fx = (float)((double)w * (351.0 / 21.0));
    float fy = (float)((double)h * (127.0 / 7.0));
    float fz = 4.0f + (float)tid;
    float p0 = fx - sPT[0], p1 = fy - sPT[1], p2 = fz - sPT[2];
    float q0 = (sP[0]*p0 + sP[1]*p1) + sP[2]*p2;
    float q1 = (sP[3]*p0 + sP[4]*p1) + sP[5]*p2;
    float q2 = (sP[6]*p0 + sP[7]*p1) + sP[8]*p2;
    float r0 = q0*q2, r1 = q1*q2, r2 = q2;
    float g0 = ((sM[0]*r0 + sM[1]*r1) + sM[2]*r2) + sTR[0];
    float g1 = ((sM[3]*r0 + sM[4]*r1) + sM[5]*r2) + sTR[1];
    float g2 = ((sM[6]*r0 + sM[7]*r1) + sM[8]*r2) + sTR[2];
    int ix = (int)((g0 + 50.0f) / 0.5f);
    int iy = (int)((g1 + 50.0f) / 0.5f);
    int iz = (int)((g2 + 10.0f) / 20.0f);
    bool kept = (ix >= 0) & (ix < NXX) & (iy >= 0) & (iy < NXY) & (iz == 0);
    sVoff[tid]  = kept ? (ix*NXY + iy) : -1;
    sDepth[tid] = depth;
  }
  __syncthreads();
  const float feat = cam_out[base + (DNUM + tid)*HW];
  float* outb = out + (size_t)b*OUT_PER_B + (size_t)tid*KVOX;
  #pragma unroll 1
  for (int d = 0; d < DNUM; d++) {
    int v = sVoff[d];
    if (v >= 0) atomicAdd(outb + v, sDepth[d] * feat);
  }
}

extern "C" void kernel_launch(void* const* d_in, const int* in_sizes, int n_in,
                              void* d_out, int out_size, void* d_ws, size_t ws_size,
                              hipStream_t stream) {
  const float* cam_out    = (const float*)d_in[0];
  const float* rots       = (const float*)d_in[1];
  const float* trans      = (const float*)d_in[2];
  const float* intrins    = (const float*)d_in[3];
  const float* post_rots  = (const float*)d_in[4];
  const float* post_trans = (const float*)d_in[5];
  float* out = (float*)d_out;
  char*  ws  = (char*)d_ws;

  // ws layout (listPW first: 8B-aligned)
  int2*  listPW  = (int2*)ws;                                   // NPTS
  float* featT   = (float*)(ws + (size_t)NPTS*8);               // PIXT*CAMC
  int*   recVox  = (int*)(featT + (size_t)PIXT*CAMC);           // NPTS
  float* recW    = (float*)(recVox + NPTS);                     // NPTS
  int*   counts  = (int*)(recW + NPTS);                         // NTILE
  int*   offsets = counts + NTILE;                              // NTILE
  int*   cursors = offsets + NTILE;                             // NTILE
  const size_t need = (size_t)((char*)(cursors + NTILE) - ws);

  if (ws_size >= need) {
    hipMemsetAsync(counts, 0, (size_t)NTILE*sizeof(int), stream);
    lss_col<<<NROW, 256, 0, stream>>>(cam_out, rots, trans, intrins,
                                      post_rots, post_trans,
                                      featT, recVox, recW, counts);
    lss_scan<<<1, 1024, 0, stream>>>(counts, offsets, cursors);
    lss_place<<<NPTS/256, 256, 0, stream>>>(recVox, recW, cursors, listPW);
    dim3 g(TPB, NB);
    lss_gatherT<<<g, 1024, 0, stream>>>(offsets, counts, listPW, featT, out);
  } else {
    float* prep = (float*)ws;   // BN*18 floats
    hipMemsetAsync(out, 0, (size_t)out_size*sizeof(float), stream);
    lss_prep<<<1, 64, 0, stream>>>(rots, intrins, post_rots, prep);
    lss_scatter_direct<<<BN * HW, 64, 0, stream>>>(cam_out, trans, post_trans, prep, out);
  }
}

// Round 9
// 89.426 us; speedup vs baseline: 2.9484x; 2.4599x over previous
//
#include <hip/hip_runtime.h>
#include <math.h>

// LiftSplatShoot constants
#define DNUM 41
#define FH 8
#define FW 22
#define CAMC 64
#define NB 8
#define NCAM 6
#define BN 48
#define NXX 200
#define NXY 200
#define KVOX 40000                // NXX*NXY (NXZ=1)
#define CAM_CH (DNUM + CAMC)      // 105
#define HW (FH * FW)              // 176
#define CAM_STRIDE (CAM_CH * HW)  // 18480
#define OUT_PER_B (CAMC * KVOX)   // 2,560,000 floats per batch (scratch & out)
#define SCRATCH_FLOATS ((size_t)NB * KVOX * CAMC)   // 20,480,000 floats = 81.92 MB
#define NXCD 8

// Replicates reference safe_inverse_3x3 in float32, same op order, no fma.
__device__ __forceinline__ void inv3x3(const float* __restrict__ m, float* __restrict__ o) {
  #pragma clang fp contract(off)
  float a=m[0], b=m[1], c=m[2];
  float d=m[3], e=m[4], f=m[5];
  float g=m[6], h=m[7], i=m[8];
  float A  =  e*i - f*h;
  float Bc = -(d*i - f*g);
  float Cc =  d*h - e*g;
  float Dc = -(b*i - c*h);
  float E  =  a*i - c*g;
  float F  = -(a*h - b*g);
  float G  =  b*f - c*e;
  float H  = -(a*f - c*d);
  float I  =  a*e - b*d;
  float det = fmaxf((a*A + b*Bc) + c*Cc, 1e-8f);
  o[0]=A/det;  o[1]=Dc/det; o[2]=G/det;
  o[3]=Bc/det; o[4]=E/det;  o[5]=H/det;
  o[6]=Cc/det; o[7]=F/det;  o[8]=I/det;
}

// XCD-pinned scratch zero: block id ≡ b (mod 8) -> all of batch b's 10.24 MB
// region is zeroed (and becomes L2-resident/owned) on one XCD.
// 5000 blocks: b = id&7, j = id>>3 in [0,625); 16 KB per block.
__global__ __launch_bounds__(256) void lss_zero(float4* __restrict__ ws4) {
  const int id = blockIdx.x;
  const int b  = id & 7;
  const int j  = id >> 3;
  const float4 z = make_float4(0.f, 0.f, 0.f, 0.f);
  float4* p = ws4 + (size_t)b*(OUT_PER_B/4) + (size_t)j*1024 + threadIdx.x;
  p[0] = z; p[256] = z; p[512] = z; p[768] = z;
}

// One 512-thread block (8 waves) per (bn, w) column, XCD-pinned by batch:
// blockIdx.x = j*8 + b  (b = batch, j = column-within-batch 0..131).
//   thread 0: computes P = inv(post_rots), M = rots @ inv(intrins)
//   wave wv (=row h): softmax + geometry for its row
//   scatter: wave wv handles depths d = wv, wv+8, ... with cross-row register
//            merge (rows hitting the same voxel share one atomic).
__global__ __launch_bounds__(512) void lss_scatter_col(const float* __restrict__ cam_out,
                                                       const float* __restrict__ rots,
                                                       const float* __restrict__ trans,
                                                       const float* __restrict__ intrins,
                                                       const float* __restrict__ post_rots,
                                                       const float* __restrict__ post_trans,
                                                       float* __restrict__ dst) {
  #pragma clang fp contract(off)
  const int blk  = blockIdx.x;        // 0 .. BN*FW-1
  const int b    = blk & 7;           // XCD-pinned batch
  const int j    = blk >> 3;          // 0..131 column within batch
  const int bn   = b*NCAM + (j / FW);
  const int w    = j - (j / FW)*FW;
  const int tid  = threadIdx.x;
  const int wv   = tid >> 6;          // wave id 0..7 == row h
  const int lane = tid & 63;

  __shared__ float sP[9], sM[9], sPT[3], sTR[3];
  __shared__ float sDep[FH][DNUM + 1];
  __shared__ int   sVox[FH][DNUM + 1];
  __shared__ float sFeat[FH][CAMC];

  // ---- inlined prep (thread 0) + small vec loads ----
  if (tid == 0) {
    float P[9], IC[9], M[9];
    inv3x3(post_rots + bn*9, P);
    inv3x3(intrins + bn*9, IC);
    const float* R = rots + bn*9;
    #pragma unroll
    for (int r = 0; r < 3; r++)
      #pragma unroll
      for (int k = 0; k < 3; k++)
        M[r*3+k] = (R[r*3+0]*IC[0+k] + R[r*3+1]*IC[3+k]) + R[r*3+2]*IC[6+k];
    #pragma unroll
    for (int q = 0; q < 9; q++) { sP[q] = P[q]; sM[q] = M[q]; }
  } else if (tid >= 8 && tid < 11) {
    sPT[tid-8]  = post_trans[bn*3 + (tid-8)];
  } else if (tid >= 11 && tid < 14) {
    sTR[tid-11] = trans[bn*3 + (tid-11)];
  }

  const int colbase = bn*CAM_STRIDE + w;   // + c*HW + h*FW

  // ---- features: 512 threads, exactly one value each ----
  {
    int fh = tid >> 6, c = tid & 63;
    sFeat[fh][c] = cam_out[colbase + (DNUM + c)*HW + fh*FW];
  }
  __syncthreads();

  const float fx = (float)((double)w * (351.0 / 21.0));

  // ---- per-row softmax + geometry: wave wv handles row h = wv ----
  {
    const int h = wv;
    float logit = (lane < DNUM) ? cam_out[colbase + lane*HW + h*FW] : -INFINITY;
    float mx = logit;
    #pragma unroll
    for (int off = 32; off >= 1; off >>= 1) mx = fmaxf(mx, __shfl_xor(mx, off, 64));
    float e = expf(logit - mx);
    float s = e;
    #pragma unroll
    for (int off = 32; off >= 1; off >>= 1) s += __shfl_xor(s, off, 64);
    if (lane < DNUM) {
      float fy = (float)((double)h * (127.0 / 7.0));
      float fz = 4.0f + (float)lane;
      float p0 = fx - sPT[0], p1 = fy - sPT[1], p2 = fz - sPT[2];
      float q0 = (sP[0]*p0 + sP[1]*p1) + sP[2]*p2;
      float q1 = (sP[3]*p0 + sP[4]*p1) + sP[5]*p2;
      float q2 = (sP[6]*p0 + sP[7]*p1) + sP[8]*p2;
      float r0 = q0*q2, r1 = q1*q2, r2 = q2;
      float g0 = ((sM[0]*r0 + sM[1]*r1) + sM[2]*r2) + sTR[0];
      float g1 = ((sM[3]*r0 + sM[4]*r1) + sM[5]*r2) + sTR[1];
      float g2 = ((sM[6]*r0 + sM[7]*r1) + sM[8]*r2) + sTR[2];
      int ix = (int)((g0 + 50.0f) / 0.5f);
      int iy = (int)((g1 + 50.0f) / 0.5f);
      int iz = (int)((g2 + 10.0f) / 20.0f);
      bool kept = (ix >= 0) & (ix < NXX) & (iy >= 0) & (iy < NXY) & (iz == 0);
      sVox[h][lane] = kept ? (ix*NXY + iy) : -1;
      sDep[h][lane] = e / s;
    }
  }
  __syncthreads();

  // ---- merged scatter: wave wv takes depths d = wv, wv+8, ...; lane = c ----
  float* __restrict__ sb = dst + (size_t)b*OUT_PER_B + lane;
  for (int d = wv; d < DNUM; d += 8) {
    unsigned done = 0;
    #pragma unroll
    for (int h = 0; h < FH; h++) {
      if ((done >> h) & 1u) continue;
      int v = sVox[h][d];            // wave-uniform (broadcast LDS read)
      if (v < 0) continue;
      float wsum = sDep[h][d] * sFeat[h][lane];
      #pragma unroll
      for (int h2 = h + 1; h2 < FH; h2++) {
        if (sVox[h2][d] == v) {
          wsum += sDep[h2][d] * sFeat[h2][lane];
          done |= 1u << h2;
        }
      }
      atomicAdd(sb + (size_t)v*CAMC, wsum);   // 64 lanes -> 4 cache lines, XCD-local
    }
  }
}

// (B, XY, C) -> (B, C, XY) tiled transpose, XCD-pinned by batch:
// 5000 blocks, b = id&7 (reads batch b's dirty lines on the XCD that owns them).
__global__ __launch_bounds__(256) void lss_transpose(const float* __restrict__ src,
                                                     float* __restrict__ out) {
  __shared__ float tile[64][65];
  const int id = blockIdx.x;
  const int b  = id & 7;
  const int v0 = (id >> 3) * 64;                  // 625 tiles per batch
  const int tx = threadIdx.x & 63;
  const int ty = threadIdx.x >> 6;                // 0..3
  const float* s = src + ((size_t)b*KVOX + v0) * CAMC;
  #pragma unroll
  for (int r = ty; r < 64; r += 4)
    tile[r][tx] = s[r*CAMC + tx];                 // coalesced
  __syncthreads();
  float* dstp = out + (size_t)b*OUT_PER_B + v0;
  #pragma unroll
  for (int r = ty; r < 64; r += 4)
    dstp[(size_t)r*KVOX + tx] = tile[tx][r];      // coalesced, bank-conflict-free
}

// ---------------- fallback (tiny ws): round-1 direct atomic path ----------------
__global__ void lss_prep(const float* __restrict__ rots,
                         const float* __restrict__ intrins,
                         const float* __restrict__ post_rots,
                         float* __restrict__ prep) {
  #pragma clang fp contract(off)
  int bn = threadIdx.x;
  if (bn >= BN) return;
  float P[9], IC[9];
  inv3x3(post_rots + bn*9, P);
  inv3x3(intrins + bn*9, IC);
  const float* R = rots + bn*9;
  float* o = prep + bn*18;
  #pragma unroll
  for (int q = 0; q < 9; q++) o[q] = P[q];
  #pragma unroll
  for (int r = 0; r < 3; r++)
    #pragma unroll
    for (int k = 0; k < 3; k++)
      o[9 + r*3 + k] = (R[r*3+0]*IC[0+k] + R[r*3+1]*IC[3+k]) + R[r*3+2]*IC[6+k];
}

__global__ __launch_bounds__(64) void lss_scatter_direct(const float* __restrict__ cam_out,
                                                         const float* __restrict__ trans,
                                                         const float* __restrict__ post_trans,
                                                         const float* __restrict__ prep,
                                                         float* __restrict__ out) {
  #pragma clang fp contract(off)
  const int blk = blockIdx.x;
  const int bn  = blk / HW;
  const int pix = blk % HW;
  const int h   = pix / FW;
  const int w   = pix % FW;
  const int b   = bn / NCAM;
  const int tid = threadIdx.x;
  __shared__ float sP[9], sM[9], sPT[3], sTR[3];
  __shared__ float sDepth[DNUM];
  __shared__ int   sVoff[DNUM];
  if (tid < 9)       sP[tid]      = prep[bn*18 + tid];
  else if (tid < 18) sM[tid-9]    = prep[bn*18 + tid];
  else if (tid < 21) sPT[tid-18]  = post_trans[bn*3 + (tid-18)];
  else if (tid < 24) sTR[tid-21]  = trans[bn*3 + (tid-21)];
  __syncthreads();
  const int base = bn*CAM_STRIDE + h*FW + w;
  float logit = (tid < DNUM) ? cam_out[base + tid*HW] : -INFINITY;
  float mx = logit;
  #pragma unroll
  for (int off = 32; off >= 1; off >>= 1) mx = fmaxf(mx, __shfl_xor(mx, off, 64));
  float e = expf(logit - mx);
  float s = e;
  #pragma unroll
  for (int off = 32; off >= 1; off >>= 1) s += __shfl_xor(s, off, 64);
  float depth = e / s;
  if (tid < DNUM) {
    float fx = (float)((double)w * (351.0 / 21.0));
    float fy = (float)((double)h * (127.0 / 7.0));
    float fz = 4.0f + (float)tid;
    float p0 = fx - sPT[0], p1 = fy - sPT[1], p2 = fz - sPT[2];
    float q0 = (sP[0]*p0 + sP[1]*p1) + sP[2]*p2;
    float q1 = (sP[3]*p0 + sP[4]*p1) + sP[5]*p2;
    float q2 = (sP[6]*p0 + sP[7]*p1) + sP[8]*p2;
    float r0 = q0*q2, r1 = q1*q2, r2 = q2;
    float g0 = ((sM[0]*r0 + sM[1]*r1) + sM[2]*r2) + sTR[0];
    float g1 = ((sM[3]*r0 + sM[4]*r1) + sM[5]*r2) + sTR[1];
    float g2 = ((sM[6]*r0 + sM[7]*r1) + sM[8]*r2) + sTR[2];
    int ix = (int)((g0 + 50.0f) / 0.5f);
    int iy = (int)((g1 + 50.0f) / 0.5f);
    int iz = (int)((g2 + 10.0f) / 20.0f);
    bool kept = (ix >= 0) & (ix < NXX) & (iy >= 0) & (iy < NXY) & (iz == 0);
    sVoff[tid]  = kept ? (ix*NXY + iy) : -1;
    sDepth[tid] = depth;
  }
  __syncthreads();
  const float feat = cam_out[base + (DNUM + tid)*HW];
  float* outb = out + (size_t)b*OUT_PER_B + (size_t)tid*KVOX;
  #pragma unroll 1
  for (int d = 0; d < DNUM; d++) {
    int v = sVoff[d];
    if (v >= 0) atomicAdd(outb + v, sDepth[d] * feat);
  }
}

extern "C" void kernel_launch(void* const* d_in, const int* in_sizes, int n_in,
                              void* d_out, int out_size, void* d_ws, size_t ws_size,
                              hipStream_t stream) {
  const float* cam_out    = (const float*)d_in[0];
  const float* rots       = (const float*)d_in[1];
  const float* trans      = (const float*)d_in[2];
  const float* intrins    = (const float*)d_in[3];
  const float* post_rots  = (const float*)d_in[4];
  const float* post_trans = (const float*)d_in[5];
  float* out = (float*)d_out;
  float* ws  = (float*)d_ws;

  const size_t scratch_bytes = SCRATCH_FLOATS * sizeof(float);
  const bool use_scratch = ws_size >= scratch_bytes;

  if (use_scratch) {
    lss_zero<<<5000, 256, 0, stream>>>((float4*)ws);
    lss_scatter_col<<<BN * FW, 512, 0, stream>>>(cam_out, rots, trans, intrins,
                                                 post_rots, post_trans, ws);
    lss_transpose<<<5000, 256, 0, stream>>>(ws, out);
  } else {
    float* prep = ws;   // BN*18 floats
    hipMemsetAsync(out, 0, (size_t)out_size * sizeof(float), stream);
    lss_prep<<<1, 64, 0, stream>>>(rots, intrins, post_rots, prep);
    lss_scatter_direct<<<BN * HW, 64, 0, stream>>>(cam_out, trans, post_trans, prep, out);
  }
}

// Round 10
// 84.811 us; speedup vs baseline: 3.1088x; 1.0544x over previous
//
#include <hip/hip_runtime.h>
#include <math.h>

// LiftSplatShoot constants
#define DNUM 41
#define FH 8
#define FW 22
#define CAMC 64
#define NB 8
#define NCAM 6
#define BN 48
#define NXX 200
#define NXY 200
#define KVOX 40000                // NXX*NXY (NXZ=1)
#define CAM_CH (DNUM + CAMC)      // 105
#define HW (FH * FW)              // 176
#define CAM_STRIDE (CAM_CH * HW)  // 18480
#define OUT_PER_B (CAMC * KVOX)   // 2,560,000 floats per batch (scratch & out)
#define SCRATCH_FLOATS ((size_t)NB * KVOX * CAMC)   // 20,480,000 floats = 81.92 MB
#define NCPB (NCAM * FW)          // 132 columns per batch
#define NCOL (NB * NCPB)          // 1056 columns total
#define PIXT (NCOL * FH)          // 8448 pixels
#define NPTS (NCOL * FH * DNUM)   // 346,368 points
#define TASKS_PB (NCPB * DNUM)    // 5412 (col,depth) tasks per batch
#define ATOM_BLKS_PB (TASKS_PB / 4)  // 1353 blocks per batch (4 waves each)

// Replicates reference safe_inverse_3x3 in float32, same op order, no fma.
__device__ __forceinline__ void inv3x3(const float* __restrict__ m, float* __restrict__ o) {
  #pragma clang fp contract(off)
  float a=m[0], b=m[1], c=m[2];
  float d=m[3], e=m[4], f=m[5];
  float g=m[6], h=m[7], i=m[8];
  float A  =  e*i - f*h;
  float Bc = -(d*i - f*g);
  float Cc =  d*h - e*g;
  float Dc = -(b*i - c*h);
  float E  =  a*i - c*g;
  float F  = -(a*h - b*g);
  float G  =  b*f - c*e;
  float H  = -(a*f - c*d);
  float I  =  a*e - b*d;
  float det = fmaxf((a*A + b*Bc) + c*Cc, 1e-8f);
  o[0]=A/det;  o[1]=Dc/det; o[2]=G/det;
  o[3]=Bc/det; o[4]=E/det;  o[5]=H/det;
  o[6]=Cc/det; o[7]=F/det;  o[8]=I/det;
}

// XCD-pinned scratch zero: block id ≡ b (mod 8); 16 KB per block.
__global__ __launch_bounds__(256) void lss_zero(float4* __restrict__ ws4) {
  const int id = blockIdx.x;
  const int b  = id & 7;
  const int j  = id >> 3;
  const float4 z = make_float4(0.f, 0.f, 0.f, 0.f);
  float4* p = ws4 + (size_t)b*(OUT_PER_B/4) + (size_t)j*1024 + threadIdx.x;
  p[0] = z; p[256] = z; p[512] = z; p[768] = z;
}

// Phase 1: one 512-thread block per column, XCD-pinned (blk = j*8 + b).
// Softmax + geometry only — emits records (vox,dep) per (col,d,h) and the
// pix-major feature transpose featT. NO float atomics here.
__global__ __launch_bounds__(512) void lss_geom(const float* __restrict__ cam_out,
                                                const float* __restrict__ rots,
                                                const float* __restrict__ trans,
                                                const float* __restrict__ intrins,
                                                const float* __restrict__ post_rots,
                                                const float* __restrict__ post_trans,
                                                float* __restrict__ featT,
                                                int2* __restrict__ recs) {
  #pragma clang fp contract(off)
  const int blk  = blockIdx.x;        // 0 .. NCOL-1
  const int b    = blk & 7;           // XCD-pinned batch
  const int j    = blk >> 3;          // 0..131 column within batch
  const int bn   = b*NCAM + (j / FW);
  const int w    = j - (j / FW)*FW;
  const int col  = b*NCPB + j;        // global column index for featT/recs
  const int tid  = threadIdx.x;
  const int wv   = tid >> 6;          // wave id 0..7 == row h
  const int lane = tid & 63;

  __shared__ float sP[9], sM[9], sPT[3], sTR[3];
  __shared__ float sDep[FH][DNUM + 1];
  __shared__ int   sVox[FH][DNUM + 1];

  if (tid == 0) {
    float P[9], IC[9], M[9];
    inv3x3(post_rots + bn*9, P);
    inv3x3(intrins + bn*9, IC);
    const float* R = rots + bn*9;
    #pragma unroll
    for (int r = 0; r < 3; r++)
      #pragma unroll
      for (int k = 0; k < 3; k++)
        M[r*3+k] = (R[r*3+0]*IC[0+k] + R[r*3+1]*IC[3+k]) + R[r*3+2]*IC[6+k];
    #pragma unroll
    for (int q = 0; q < 9; q++) { sP[q] = P[q]; sM[q] = M[q]; }
  } else if (tid >= 8 && tid < 11) {
    sPT[tid-8]  = post_trans[bn*3 + (tid-8)];
  } else if (tid >= 11 && tid < 14) {
    sTR[tid-11] = trans[bn*3 + (tid-11)];
  }

  const int colbase = bn*CAM_STRIDE + w;   // + c*HW + h*FW

  // featT: global->reg->global, write side fully coalesced (256B runs)
  {
    int fh = tid >> 6, c = tid & 63;
    float fv = cam_out[colbase + (DNUM + c)*HW + fh*FW];
    featT[((size_t)(col*FH + fh))*CAMC + c] = fv;
  }
  __syncthreads();

  const float fx = (float)((double)w * (351.0 / 21.0));

  // per-row softmax + geometry: wave wv handles row h = wv (lane = depth)
  {
    const int h = wv;
    float logit = (lane < DNUM) ? cam_out[colbase + lane*HW + h*FW] : -INFINITY;
    float mx = logit;
    #pragma unroll
    for (int off = 32; off >= 1; off >>= 1) mx = fmaxf(mx, __shfl_xor(mx, off, 64));
    float e = expf(logit - mx);
    float s = e;
    #pragma unroll
    for (int off = 32; off >= 1; off >>= 1) s += __shfl_xor(s, off, 64);
    if (lane < DNUM) {
      float fy = (float)((double)h * (127.0 / 7.0));
      float fz = 4.0f + (float)lane;
      float p0 = fx - sPT[0], p1 = fy - sPT[1], p2 = fz - sPT[2];
      float q0 = (sP[0]*p0 + sP[1]*p1) + sP[2]*p2;
      float q1 = (sP[3]*p0 + sP[4]*p1) + sP[5]*p2;
      float q2 = (sP[6]*p0 + sP[7]*p1) + sP[8]*p2;
      float r0 = q0*q2, r1 = q1*q2, r2 = q2;
      float g0 = ((sM[0]*r0 + sM[1]*r1) + sM[2]*r2) + sTR[0];
      float g1 = ((sM[3]*r0 + sM[4]*r1) + sM[5]*r2) + sTR[1];
      float g2 = ((sM[6]*r0 + sM[7]*r1) + sM[8]*r2) + sTR[2];
      int ix = (int)((g0 + 50.0f) / 0.5f);
      int iy = (int)((g1 + 50.0f) / 0.5f);
      int iz = (int)((g2 + 10.0f) / 20.0f);
      bool kept = (ix >= 0) & (ix < NXX) & (iy >= 0) & (iy < NXY) & (iz == 0);
      sVox[h][lane] = kept ? (ix*NXY + iy) : -1;
      sDep[h][lane] = e / s;
    }
  }
  __syncthreads();

  // records: rec[(col*41 + d)*8 + h], coalesced 8B writes (e = d*8+h)
  int2* __restrict__ rc = recs + (size_t)col*DNUM*FH;
  for (int e = tid; e < DNUM*FH; e += 512) {
    int d = e >> 3, h = e & 7;
    rc[e] = make_int2(sVox[h][d], __float_as_int(sDep[h][d]));
  }
}

// Phase 2: pure atomic kernel. One wave per (col,d) task; 4 waves/block;
// grid = 1353*8, XCD-pinned (blk&7 = b). Register-only h-merge, then
// coalesced merged atomics (64 lanes -> 4 cache lines, XCD-local).
__global__ __launch_bounds__(256) void lss_atomic(const int2* __restrict__ recs,
                                                  const float* __restrict__ featT,
                                                  float* __restrict__ dst) {
  const int blk  = blockIdx.x;
  const int b    = blk & 7;
  const int q    = blk >> 3;          // 0..1352
  const int wv   = (threadIdx.x >> 6);
  const int lane = threadIdx.x & 63;
  const int task = q*4 + wv;          // 0..5411
  const int j    = task / DNUM;
  const int d    = task - j*DNUM;
  const int col  = b*NCPB + j;

  // uniform 64B load of the 8 (vox,dep) records for this (col,d)
  const int2* __restrict__ r8 = recs + ((size_t)col*DNUM + d)*FH;
  int   vox[FH];
  float dep[FH];
  #pragma unroll
  for (int h = 0; h < FH; h++) {
    int2 e = r8[h];
    vox[h] = e.x;
    dep[h] = __int_as_float(e.y);
  }

  // prefetch the 8 feature rows (256B coalesced each, L2-resident)
  float f[FH];
  const float* __restrict__ ft = featT + (size_t)col*FH*CAMC + lane;
  #pragma unroll
  for (int h = 0; h < FH; h++) f[h] = ft[h*CAMC];

  float* __restrict__ sb = dst + (size_t)b*OUT_PER_B + lane;
  unsigned done = 0;
  #pragma unroll
  for (int h = 0; h < FH; h++) {
    if ((done >> h) & 1u) continue;
    int v = vox[h];                   // register, wave-uniform
    if (v < 0) continue;
    float wsum = dep[h] * f[h];
    #pragma unroll
    for (int h2 = h + 1; h2 < FH; h2++) {
      if (vox[h2] == v) {
        wsum += dep[h2] * f[h2];
        done |= 1u << h2;
      }
    }
    atomicAdd(sb + (size_t)v*CAMC, wsum);
  }
}

// (B, XY, C) -> (B, C, XY) tiled transpose, XCD-pinned by batch.
__global__ __launch_bounds__(256) void lss_transpose(const float* __restrict__ src,
                                                     float* __restrict__ out) {
  __shared__ float tile[64][65];
  const int id = blockIdx.x;
  const int b  = id & 7;
  const int v0 = (id >> 3) * 64;                  // 625 tiles per batch
  const int tx = threadIdx.x & 63;
  const int ty = threadIdx.x >> 6;                // 0..3
  const float* s = src + ((size_t)b*KVOX + v0) * CAMC;
  #pragma unroll
  for (int r = ty; r < 64; r += 4)
    tile[r][tx] = s[r*CAMC + tx];                 // coalesced
  __syncthreads();
  float* dstp = out + (size_t)b*OUT_PER_B + v0;
  #pragma unroll
  for (int r = ty; r < 64; r += 4)
    dstp[(size_t)r*KVOX + tx] = tile[tx][r];      // coalesced, bank-conflict-free
}

// ---------------- fallback (tiny ws): round-1 direct atomic path ----------------
__global__ void lss_prep(const float* __restrict__ rots,
                         const float* __restrict__ intrins,
                         const float* __restrict__ post_rots,
                         float* __restrict__ prep) {
  #pragma clang fp contract(off)
  int bn = threadIdx.x;
  if (bn >= BN) return;
  float P[9], IC[9];
  inv3x3(post_rots + bn*9, P);
  inv3x3(intrins + bn*9, IC);
  const float* R = rots + bn*9;
  float* o = prep + bn*18;
  #pragma unroll
  for (int q = 0; q < 9; q++) o[q] = P[q];
  #pragma unroll
  for (int r = 0; r < 3; r++)
    #pragma unroll
    for (int k = 0; k < 3; k++)
      o[9 + r*3 + k] = (R[r*3+0]*IC[0+k] + R[r*3+1]*IC[3+k]) + R[r*3+2]*IC[6+k];
}

__global__ __launch_bounds__(64) void lss_scatter_direct(const float* __restrict__ cam_out,
                                                         const float* __restrict__ trans,
                                                         const float* __restrict__ post_trans,
                                                         const float* __restrict__ prep,
                                                         float* __restrict__ out) {
  #pragma clang fp contract(off)
  const int blk = blockIdx.x;
  const int bn  = blk / HW;
  const int pix = blk % HW;
  const int h   = pix / FW;
  const int w   = pix % FW;
  const int b   = bn / NCAM;
  const int tid = threadIdx.x;
  __shared__ float sP[9], sM[9], sPT[3], sTR[3];
  __shared__ float sDepth[DNUM];
  __shared__ int   sVoff[DNUM];
  if (tid < 9)       sP[tid]      = prep[bn*18 + tid];
  else if (tid < 18) sM[tid-9]    = prep[bn*18 + tid];
  else if (tid < 21) sPT[tid-18]  = post_trans[bn*3 + (tid-18)];
  else if (tid < 24) sTR[tid-21]  = trans[bn*3 + (tid-21)];
  __syncthreads();
  const int base = bn*CAM_STRIDE + h*FW + w;
  float logit = (tid < DNUM) ? cam_out[base + tid*HW] : -INFINITY;
  float mx = logit;
  #pragma unroll
  for (int off = 32; off >= 1; off >>= 1) mx = fmaxf(mx, __shfl_xor(mx, off, 64));
  float e = expf(logit - mx);
  float s = e;
  #pragma unroll
  for (int off = 32; off >= 1; off >>= 1) s += __shfl_xor(s, off, 64);
  float depth = e / s;
  if (tid < DNUM) {
    float fx = (float)((double)w * (351.0 / 21.0));
    float fy = (float)((double)h * (127.0 / 7.0));
    float fz = 4.0f + (float)tid;
    float p0 = fx - sPT[0], p1 = fy - sPT[1], p2 = fz - sPT[2];
    float q0 = (sP[0]*p0 + sP[1]*p1) + sP[2]*p2;
    float q1 = (sP[3]*p0 + sP[4]*p1) + sP[5]*p2;
    float q2 = (sP[6]*p0 + sP[7]*p1) + sP[8]*p2;
    float r0 = q0*q2, r1 = q1*q2, r2 = q2;
    float g0 = ((sM[0]*r0 + sM[1]*r1) + sM[2]*r2) + sTR[0];
    float g1 = ((sM[3]*r0 + sM[4]*r1) + sM[5]*r2) + sTR[1];
    float g2 = ((sM[6]*r0 + sM[7]*r1) + sM[8]*r2) + sTR[2];
    int ix = (int)((g0 + 50.0f) / 0.5f);
    int iy = (int)((g1 + 50.0f) / 0.5f);
    int iz = (int)((g2 + 10.0f) / 20.0f);
    bool kept = (ix >= 0) & (ix < NXX) & (iy >= 0) & (iy < NXY) & (iz == 0);
    sVoff[tid]  = kept ? (ix*NXY + iy) : -1;
    sDepth[tid] = depth;
  }
  __syncthreads();
  const float feat = cam_out[base + (DNUM + tid)*HW];
  float* outb = out + (size_t)b*OUT_PER_B + (size_t)tid*KVOX;
  #pragma unroll 1
  for (int d = 0; d < DNUM; d++) {
    int v = sVoff[d];
    if (v >= 0) atomicAdd(outb + v, sDepth[d] * feat);
  }
}

extern "C" void kernel_launch(void* const* d_in, const int* in_sizes, int n_in,
                              void* d_out, int out_size, void* d_ws, size_t ws_size,
                              hipStream_t stream) {
  const float* cam_out    = (const float*)d_in[0];
  const float* rots       = (const float*)d_in[1];
  const float* trans      = (const float*)d_in[2];
  const float* intrins    = (const float*)d_in[3];
  const float* post_rots  = (const float*)d_in[4];
  const float* post_trans = (const float*)d_in[5];
  float* out = (float*)d_out;
  char*  ws  = (char*)d_ws;

  // ws layout: scratch (82 MB) | featT (2.2 MB) | recs (2.8 MB)
  float* scratch = (float*)ws;
  float* featT   = scratch + SCRATCH_FLOATS;                 // PIXT*CAMC floats
  int2*  recs    = (int2*)(featT + (size_t)PIXT*CAMC);       // NPTS int2 (8B-aligned)
  const size_t need = SCRATCH_FLOATS*4 + (size_t)PIXT*CAMC*4 + (size_t)NPTS*8;

  if (ws_size >= need) {
    lss_zero<<<5000, 256, 0, stream>>>((float4*)scratch);
    lss_geom<<<NCOL, 512, 0, stream>>>(cam_out, rots, trans, intrins,
                                       post_rots, post_trans, featT, recs);
    lss_atomic<<<ATOM_BLKS_PB * 8, 256, 0, stream>>>(recs, featT, scratch);
    lss_transpose<<<5000, 256, 0, stream>>>(scratch, out);
  } else {
    float* prep = (float*)ws;   // BN*18 floats
    hipMemsetAsync(out, 0, (size_t)out_size * sizeof(float), stream);
    lss_prep<<<1, 64, 0, stream>>>(rots, intrins, post_rots, prep);
    lss_scatter_direct<<<BN * HW, 64, 0, stream>>>(cam_out, trans, post_trans, prep, out);
  }
}

// Round 11
// 81.685 us; speedup vs baseline: 3.2278x; 1.0383x over previous
//
#include <hip/hip_runtime.h>
#include <math.h>

// LiftSplatShoot constants
#define DNUM 41
#define FH 8
#define FW 22
#define CAMC 64
#define NB 8
#define NCAM 6
#define BN 48
#define NXX 200
#define NXY 200
#define KVOX 40000                // NXX*NXY (NXZ=1)
#define CAM_CH (DNUM + CAMC)      // 105
#define HW (FH * FW)              // 176
#define CAM_STRIDE (CAM_CH * HW)  // 18480
#define OUT_PER_B (CAMC * KVOX)   // 2,560,000 floats per batch (scratch & out)
#define SCRATCH_FLOATS ((size_t)NB * KVOX * CAMC)   // 20,480,000 floats = 81.92 MB
#define NCPB (NCAM * FW)          // 132 columns per batch
#define NCOL (NB * NCPB)          // 1056 columns total
#define PIXT (NCOL * FH)          // 8448 pixels
#define NPTS (NCOL * FH * DNUM)   // 346,368 points
#define TASKS_PB (NCPB * DNUM)    // 5412 (col,depth) tasks per batch
#define ATOM_BLKS_PB (TASKS_PB / 4)  // 1353 blocks per batch (4 waves each)
#define TPB 625                   // tiles (64 voxels) per batch
#define MWPB 20                   // bitmap words per batch (20*32 >= 625)
#define MWORDS (NB * MWPB)        // 160 words total

// Replicates reference safe_inverse_3x3 in float32, same op order, no fma.
__device__ __forceinline__ void inv3x3(const float* __restrict__ m, float* __restrict__ o) {
  #pragma clang fp contract(off)
  float a=m[0], b=m[1], c=m[2];
  float d=m[3], e=m[4], f=m[5];
  float g=m[6], h=m[7], i=m[8];
  float A  =  e*i - f*h;
  float Bc = -(d*i - f*g);
  float Cc =  d*h - e*g;
  float Dc = -(b*i - c*h);
  float E  =  a*i - c*g;
  float F  = -(a*h - b*g);
  float G  =  b*f - c*e;
  float H  = -(a*f - c*d);
  float I  =  a*e - b*d;
  float det = fmaxf((a*A + b*Bc) + c*Cc, 1e-8f);
  o[0]=A/det;  o[1]=Dc/det; o[2]=G/det;
  o[3]=Bc/det; o[4]=E/det;  o[5]=H/det;
  o[6]=Cc/det; o[7]=F/det;  o[8]=I/det;
}

// XCD-pinned scratch zero + dirty-bitmap clear. Block id ≡ b (mod 8).
__global__ __launch_bounds__(256) void lss_zero(float4* __restrict__ ws4,
                                                unsigned* __restrict__ dirty) {
  const int id = blockIdx.x;
  if (id < 8 && threadIdx.x < MWPB)
    dirty[id*MWPB + threadIdx.x] = 0u;   // id == batch here: clear its 20 words
  const int b  = id & 7;
  const int j  = id >> 3;
  const float4 z = make_float4(0.f, 0.f, 0.f, 0.f);
  float4* p = ws4 + (size_t)b*(OUT_PER_B/4) + (size_t)j*1024 + threadIdx.x;
  p[0] = z; p[256] = z; p[512] = z; p[768] = z;
}

// Phase 1: one 512-thread block per column, XCD-pinned (blk = j*8 + b).
// Softmax + geometry -> records (vox,dep), featT, and the dirty-tile bitmap.
__global__ __launch_bounds__(512) void lss_geom(const float* __restrict__ cam_out,
                                                const float* __restrict__ rots,
                                                const float* __restrict__ trans,
                                                const float* __restrict__ intrins,
                                                const float* __restrict__ post_rots,
                                                const float* __restrict__ post_trans,
                                                float* __restrict__ featT,
                                                int2* __restrict__ recs,
                                                unsigned* __restrict__ dirty) {
  #pragma clang fp contract(off)
  const int blk  = blockIdx.x;        // 0 .. NCOL-1
  const int b    = blk & 7;           // XCD-pinned batch
  const int j    = blk >> 3;          // 0..131 column within batch
  const int bn   = b*NCAM + (j / FW);
  const int w    = j - (j / FW)*FW;
  const int col  = b*NCPB + j;        // global column index for featT/recs
  const int tid  = threadIdx.x;
  const int wv   = tid >> 6;          // wave id 0..7 == row h
  const int lane = tid & 63;

  __shared__ float sP[9], sM[9], sPT[3], sTR[3];
  __shared__ float sDep[FH][DNUM + 1];
  __shared__ int   sVox[FH][DNUM + 1];
  __shared__ unsigned sMask[MWPB];

  if (tid == 0) {
    float P[9], IC[9], M[9];
    inv3x3(post_rots + bn*9, P);
    inv3x3(intrins + bn*9, IC);
    const float* R = rots + bn*9;
    #pragma unroll
    for (int r = 0; r < 3; r++)
      #pragma unroll
      for (int k = 0; k < 3; k++)
        M[r*3+k] = (R[r*3+0]*IC[0+k] + R[r*3+1]*IC[3+k]) + R[r*3+2]*IC[6+k];
    #pragma unroll
    for (int q = 0; q < 9; q++) { sP[q] = P[q]; sM[q] = M[q]; }
  } else if (tid >= 8 && tid < 11) {
    sPT[tid-8]  = post_trans[bn*3 + (tid-8)];
  } else if (tid >= 11 && tid < 14) {
    sTR[tid-11] = trans[bn*3 + (tid-11)];
  } else if (tid >= 64 && tid < 64 + MWPB) {
    sMask[tid-64] = 0u;
  }

  const int colbase = bn*CAM_STRIDE + w;   // + c*HW + h*FW

  // featT: global->reg->global, write side fully coalesced (256B runs)
  {
    int fh = tid >> 6, c = tid & 63;
    float fv = cam_out[colbase + (DNUM + c)*HW + fh*FW];
    featT[((size_t)(col*FH + fh))*CAMC + c] = fv;
  }
  __syncthreads();

  const float fx = (float)((double)w * (351.0 / 21.0));

  // per-row softmax + geometry: wave wv handles row h = wv (lane = depth)
  {
    const int h = wv;
    float logit = (lane < DNUM) ? cam_out[colbase + lane*HW + h*FW] : -INFINITY;
    float mx = logit;
    #pragma unroll
    for (int off = 32; off >= 1; off >>= 1) mx = fmaxf(mx, __shfl_xor(mx, off, 64));
    float e = expf(logit - mx);
    float s = e;
    #pragma unroll
    for (int off = 32; off >= 1; off >>= 1) s += __shfl_xor(s, off, 64);
    if (lane < DNUM) {
      float fy = (float)((double)h * (127.0 / 7.0));
      float fz = 4.0f + (float)lane;
      float p0 = fx - sPT[0], p1 = fy - sPT[1], p2 = fz - sPT[2];
      float q0 = (sP[0]*p0 + sP[1]*p1) + sP[2]*p2;
      float q1 = (sP[3]*p0 + sP[4]*p1) + sP[5]*p2;
      float q2 = (sP[6]*p0 + sP[7]*p1) + sP[8]*p2;
      float r0 = q0*q2, r1 = q1*q2, r2 = q2;
      float g0 = ((sM[0]*r0 + sM[1]*r1) + sM[2]*r2) + sTR[0];
      float g1 = ((sM[3]*r0 + sM[4]*r1) + sM[5]*r2) + sTR[1];
      float g2 = ((sM[6]*r0 + sM[7]*r1) + sM[8]*r2) + sTR[2];
      int ix = (int)((g0 + 50.0f) / 0.5f);
      int iy = (int)((g1 + 50.0f) / 0.5f);
      int iz = (int)((g2 + 10.0f) / 20.0f);
      bool kept = (ix >= 0) & (ix < NXX) & (iy >= 0) & (iy < NXY) & (iz == 0);
      int v = ix*NXY + iy;
      sVox[h][lane] = kept ? v : -1;
      sDep[h][lane] = e / s;
      if (kept) {
        int t = v >> 6;
        atomicOr(&sMask[t >> 5], 1u << (t & 31));   // LDS dedup
      }
    }
  }
  __syncthreads();

  // records: rec[(col*41 + d)*8 + h], coalesced 8B writes (e = d*8+h)
  int2* __restrict__ rc = recs + (size_t)col*DNUM*FH;
  for (int e = tid; e < DNUM*FH; e += 512) {
    int d = e >> 3, h = e & 7;
    rc[e] = make_int2(sVox[h][d], __float_as_int(sDep[h][d]));
  }
  // publish dirty bitmap (<=20 global atomicOr per block)
  if (tid < MWPB && sMask[tid])
    atomicOr(&dirty[b*MWPB + tid], sMask[tid]);
}

// Phase 2: pure atomic kernel. One wave per (col,d) task; 4 waves/block;
// grid = 1353*8, XCD-pinned (blk&7 = b). Register-only h-merge, then
// coalesced merged atomics (64 lanes -> 4 cache lines, XCD-local).
__global__ __launch_bounds__(256) void lss_atomic(const int2* __restrict__ recs,
                                                  const float* __restrict__ featT,
                                                  float* __restrict__ dst) {
  const int blk  = blockIdx.x;
  const int b    = blk & 7;
  const int q    = blk >> 3;          // 0..1352
  const int wv   = (threadIdx.x >> 6);
  const int lane = threadIdx.x & 63;
  const int task = q*4 + wv;          // 0..5411
  const int j    = task / DNUM;
  const int d    = task - j*DNUM;
  const int col  = b*NCPB + j;

  const int2* __restrict__ r8 = recs + ((size_t)col*DNUM + d)*FH;
  int   vox[FH];
  float dep[FH];
  #pragma unroll
  for (int h = 0; h < FH; h++) {
    int2 e = r8[h];
    vox[h] = e.x;
    dep[h] = __int_as_float(e.y);
  }

  float f[FH];
  const float* __restrict__ ft = featT + (size_t)col*FH*CAMC + lane;
  #pragma unroll
  for (int h = 0; h < FH; h++) f[h] = ft[h*CAMC];

  float* __restrict__ sb = dst + (size_t)b*OUT_PER_B + lane;
  unsigned done = 0;
  #pragma unroll
  for (int h = 0; h < FH; h++) {
    if ((done >> h) & 1u) continue;
    int v = vox[h];                   // register, wave-uniform
    if (v < 0) continue;
    float wsum = dep[h] * f[h];
    #pragma unroll
    for (int h2 = h + 1; h2 < FH; h2++) {
      if (vox[h2] == v) {
        wsum += dep[h2] * f[h2];
        done |= 1u << h2;
      }
    }
    atomicAdd(sb + (size_t)v*CAMC, wsum);
  }
}

// (B, XY, C) -> (B, C, XY) tiled transpose, XCD-pinned by batch.
// Clean tiles (dirty bit unset) write zeros directly — no scratch read.
__global__ __launch_bounds__(256) void lss_transpose(const float* __restrict__ src,
                                                     const unsigned* __restrict__ dirty,
                                                     float* __restrict__ out) {
  __shared__ float tile[64][65];
  const int id = blockIdx.x;
  const int b  = id & 7;
  const int t  = id >> 3;                         // tile 0..624
  const int v0 = t * 64;
  const int tx = threadIdx.x & 63;
  const int ty = threadIdx.x >> 6;                // 0..3
  float* dstp = out + (size_t)b*OUT_PER_B + v0;

  const bool isDirty = (dirty[b*MWPB + (t >> 5)] >> (t & 31)) & 1u;
  if (!isDirty) {
    #pragma unroll
    for (int r = ty; r < 64; r += 4)
      dstp[(size_t)r*KVOX + tx] = 0.0f;           // coalesced zero-fill
    return;
  }

  const float* s = src + ((size_t)b*KVOX + v0) * CAMC;
  #pragma unroll
  for (int r = ty; r < 64; r += 4)
    tile[r][tx] = s[r*CAMC + tx];                 // coalesced
  __syncthreads();
  #pragma unroll
  for (int r = ty; r < 64; r += 4)
    dstp[(size_t)r*KVOX + tx] = tile[tx][r];      // coalesced, bank-conflict-free
}

// ---------------- fallback (tiny ws): round-1 direct atomic path ----------------
__global__ void lss_prep(const float* __restrict__ rots,
                         const float* __restrict__ intrins,
                         const float* __restrict__ post_rots,
                         float* __restrict__ prep) {
  #pragma clang fp contract(off)
  int bn = threadIdx.x;
  if (bn >= BN) return;
  float P[9], IC[9];
  inv3x3(post_rots + bn*9, P);
  inv3x3(intrins + bn*9, IC);
  const float* R = rots + bn*9;
  float* o = prep + bn*18;
  #pragma unroll
  for (int q = 0; q < 9; q++) o[q] = P[q];
  #pragma unroll
  for (int r = 0; r < 3; r++)
    #pragma unroll
    for (int k = 0; k < 3; k++)
      o[9 + r*3 + k] = (R[r*3+0]*IC[0+k] + R[r*3+1]*IC[3+k]) + R[r*3+2]*IC[6+k];
}

__global__ __launch_bounds__(64) void lss_scatter_direct(const float* __restrict__ cam_out,
                                                         const float* __restrict__ trans,
                                                         const float* __restrict__ post_trans,
                                                         const float* __restrict__ prep,
                                                         float* __restrict__ out) {
  #pragma clang fp contract(off)
  const int blk = blockIdx.x;
  const int bn  = blk / HW;
  const int pix = blk % HW;
  const int h   = pix / FW;
  const int w   = pix % FW;
  const int b   = bn / NCAM;
  const int tid = threadIdx.x;
  __shared__ float sP[9], sM[9], sPT[3], sTR[3];
  __shared__ float sDepth[DNUM];
  __shared__ int   sVoff[DNUM];
  if (tid < 9)       sP[tid]      = prep[bn*18 + tid];
  else if (tid < 18) sM[tid-9]    = prep[bn*18 + tid];
  else if (tid < 21) sPT[tid-18]  = post_trans[bn*3 + (tid-18)];
  else if (tid < 24) sTR[tid-21]  = trans[bn*3 + (tid-21)];
  __syncthreads();
  const int base = bn*CAM_STRIDE + h*FW + w;
  float logit = (tid < DNUM) ? cam_out[base + tid*HW] : -INFINITY;
  float mx = logit;
  #pragma unroll
  for (int off = 32; off >= 1; off >>= 1) mx = fmaxf(mx, __shfl_xor(mx, off, 64));
  float e = expf(logit - mx);
  float s = e;
  #pragma unroll
  for (int off = 32; off >= 1; off >>= 1) s += __shfl_xor(s, off, 64);
  float depth = e / s;
  if (tid < DNUM) {
    float fx = (float)((double)w * (351.0 / 21.0));
    float fy = (float)((double)h * (127.0 / 7.0));
    float fz = 4.0f + (float)tid;
    float p0 = fx - sPT[0], p1 = fy - sPT[1], p2 = fz - sPT[2];
    float q0 = (sP[0]*p0 + sP[1]*p1) + sP[2]*p2;
    float q1 = (sP[3]*p0 + sP[4]*p1) + sP[5]*p2;
    float q2 = (sP[6]*p0 + sP[7]*p1) + sP[8]*p2;
    float r0 = q0*q2, r1 = q1*q2, r2 = q2;
    float g0 = ((sM[0]*r0 + sM[1]*r1) + sM[2]*r2) + sTR[0];
    float g1 = ((sM[3]*r0 + sM[4]*r1) + sM[5]*r2) + sTR[1];
    float g2 = ((sM[6]*r0 + sM[7]*r1) + sM[8]*r2) + sTR[2];
    int ix = (int)((g0 + 50.0f) / 0.5f);
    int iy = (int)((g1 + 50.0f) / 0.5f);
    int iz = (int)((g2 + 10.0f) / 20.0f);
    bool kept = (ix >= 0) & (ix < NXX) & (iy >= 0) & (iy < NXY) & (iz == 0);
    sVoff[tid]  = kept ? (ix*NXY + iy) : -1;
    sDepth[tid] = depth;
  }
  __syncthreads();
  const float feat = cam_out[base + (DNUM + tid)*HW];
  float* outb = out + (size_t)b*OUT_PER_B + (size_t)tid*KVOX;
  #pragma unroll 1
  for (int d = 0; d < DNUM; d++) {
    int v = sVoff[d];
    if (v >= 0) atomicAdd(outb + v, sDepth[d] * feat);
  }
}

extern "C" void kernel_launch(void* const* d_in, const int* in_sizes, int n_in,
                              void* d_out, int out_size, void* d_ws, size_t ws_size,
                              hipStream_t stream) {
  const float* cam_out    = (const float*)d_in[0];
  const float* rots       = (const float*)d_in[1];
  const float* trans      = (const float*)d_in[2];
  const float* intrins    = (const float*)d_in[3];
  const float* post_rots  = (const float*)d_in[4];
  const float* post_trans = (const float*)d_in[5];
  float* out = (float*)d_out;
  char*  ws  = (char*)d_ws;

  // ws layout: scratch (82 MB) | featT (2.2 MB) | recs (2.8 MB) | dirty (640 B)
  float*    scratch = (float*)ws;
  float*    featT   = scratch + SCRATCH_FLOATS;              // PIXT*CAMC floats
  int2*     recs    = (int2*)(featT + (size_t)PIXT*CAMC);    // NPTS int2 (8B-aligned)
  unsigned* dirty   = (unsigned*)(recs + NPTS);              // MWORDS
  const size_t need = SCRATCH_FLOATS*4 + (size_t)PIXT*CAMC*4 + (size_t)NPTS*8
                      + MWORDS*4;

  if (ws_size >= need) {
    lss_zero<<<5000, 256, 0, stream>>>((float4*)scratch, dirty);
    lss_geom<<<NCOL, 512, 0, stream>>>(cam_out, rots, trans, intrins,
                                       post_rots, post_trans, featT, recs, dirty);
    lss_atomic<<<ATOM_BLKS_PB * 8, 256, 0, stream>>>(recs, featT, scratch);
    lss_transpose<<<5000, 256, 0, stream>>>(scratch, dirty, out);
  } else {
    float* prep = (float*)ws;   // BN*18 floats
    hipMemsetAsync(out, 0, (size_t)out_size * sizeof(float), stream);
    lss_prep<<<1, 64, 0, stream>>>(rots, intrins, post_rots, prep);
    lss_scatter_direct<<<BN * HW, 64, 0, stream>>>(cam_out, trans, post_trans, prep, out);
  }
}

// Round 12
// 78.718 us; speedup vs baseline: 3.3495x; 1.0377x over previous
//
#include <hip/hip_runtime.h>
#include <math.h>

// LiftSplatShoot constants
#define DNUM 41
#define FH 8
#define FW 22
#define CAMC 64
#define NB 8
#define NCAM 6
#define BN 48
#define NXX 200
#define NXY 200
#define KVOX 40000                // NXX*NXY (NXZ=1)
#define CAM_CH (DNUM + CAMC)      // 105
#define HW (FH * FW)              // 176
#define CAM_STRIDE (CAM_CH * HW)  // 18480
#define OUT_PER_B (CAMC * KVOX)   // 2,560,000 floats per batch (scratch & out)
#define SCRATCH_FLOATS ((size_t)NB * KVOX * CAMC)   // 20,480,000 floats = 81.92 MB
#define NCPB (NCAM * FW)          // 132 columns per batch
#define NCOL (NB * NCPB)          // 1056 columns total
#define PIXT (NCOL * FH)          // 8448 pixels
#define NPTS (NCOL * FH * DNUM)   // 346,368 points
#define TASKS_PB (NCPB * DNUM)    // 5412 (col,depth) tasks per batch
#define ATOM_BLKS_PB (TASKS_PB / 4)  // 1353 blocks per batch (4 waves each)
#define TPB 625                   // tiles (64 voxels) per batch
#define MWPB 20                   // bitmap words per batch (20*32 >= 625)
#define MWORDS (NB * MWPB)        // 160 words total

// Replicates reference safe_inverse_3x3 in float32, same op order, no fma.
__device__ __forceinline__ void inv3x3(const float* __restrict__ m, float* __restrict__ o) {
  #pragma clang fp contract(off)
  float a=m[0], b=m[1], c=m[2];
  float d=m[3], e=m[4], f=m[5];
  float g=m[6], h=m[7], i=m[8];
  float A  =  e*i - f*h;
  float Bc = -(d*i - f*g);
  float Cc =  d*h - e*g;
  float Dc = -(b*i - c*h);
  float E  =  a*i - c*g;
  float F  = -(a*h - b*g);
  float G  =  b*f - c*e;
  float H  = -(a*f - c*d);
  float I  =  a*e - b*d;
  float det = fmaxf((a*A + b*Bc) + c*Cc, 1e-8f);
  o[0]=A/det;  o[1]=Dc/det; o[2]=G/det;
  o[3]=Bc/det; o[4]=E/det;  o[5]=H/det;
  o[6]=Cc/det; o[7]=F/det;  o[8]=I/det;
}

// Phase 1: one 512-thread block per column, XCD-pinned (blk = j*8 + b).
// Softmax + geometry -> records (vox,dep), featT, and the dirty-tile bitmap.
__global__ __launch_bounds__(512) void lss_geom(const float* __restrict__ cam_out,
                                                const float* __restrict__ rots,
                                                const float* __restrict__ trans,
                                                const float* __restrict__ intrins,
                                                const float* __restrict__ post_rots,
                                                const float* __restrict__ post_trans,
                                                float* __restrict__ featT,
                                                int2* __restrict__ recs,
                                                unsigned* __restrict__ dirty) {
  #pragma clang fp contract(off)
  const int blk  = blockIdx.x;        // 0 .. NCOL-1
  const int b    = blk & 7;           // XCD-pinned batch
  const int j    = blk >> 3;          // 0..131 column within batch
  const int bn   = b*NCAM + (j / FW);
  const int w    = j - (j / FW)*FW;
  const int col  = b*NCPB + j;        // global column index for featT/recs
  const int tid  = threadIdx.x;
  const int wv   = tid >> 6;          // wave id 0..7 == row h
  const int lane = tid & 63;

  __shared__ float sP[9], sM[9], sPT[3], sTR[3];
  __shared__ float sDep[FH][DNUM + 1];
  __shared__ int   sVox[FH][DNUM + 1];
  __shared__ unsigned sMask[MWPB];

  if (tid == 0) {
    float P[9], IC[9], M[9];
    inv3x3(post_rots + bn*9, P);
    inv3x3(intrins + bn*9, IC);
    const float* R = rots + bn*9;
    #pragma unroll
    for (int r = 0; r < 3; r++)
      #pragma unroll
      for (int k = 0; k < 3; k++)
        M[r*3+k] = (R[r*3+0]*IC[0+k] + R[r*3+1]*IC[3+k]) + R[r*3+2]*IC[6+k];
    #pragma unroll
    for (int q = 0; q < 9; q++) { sP[q] = P[q]; sM[q] = M[q]; }
  } else if (tid >= 8 && tid < 11) {
    sPT[tid-8]  = post_trans[bn*3 + (tid-8)];
  } else if (tid >= 11 && tid < 14) {
    sTR[tid-11] = trans[bn*3 + (tid-11)];
  } else if (tid >= 64 && tid < 64 + MWPB) {
    sMask[tid-64] = 0u;
  }

  const int colbase = bn*CAM_STRIDE + w;   // + c*HW + h*FW

  // featT: global->reg->global, write side fully coalesced (256B runs)
  {
    int fh = tid >> 6, c = tid & 63;
    float fv = cam_out[colbase + (DNUM + c)*HW + fh*FW];
    featT[((size_t)(col*FH + fh))*CAMC + c] = fv;
  }
  __syncthreads();

  const float fx = (float)((double)w * (351.0 / 21.0));

  // per-row softmax + geometry: wave wv handles row h = wv (lane = depth)
  {
    const int h = wv;
    float logit = (lane < DNUM) ? cam_out[colbase + lane*HW + h*FW] : -INFINITY;
    float mx = logit;
    #pragma unroll
    for (int off = 32; off >= 1; off >>= 1) mx = fmaxf(mx, __shfl_xor(mx, off, 64));
    float e = expf(logit - mx);
    float s = e;
    #pragma unroll
    for (int off = 32; off >= 1; off >>= 1) s += __shfl_xor(s, off, 64);
    if (lane < DNUM) {
      float fy = (float)((double)h * (127.0 / 7.0));
      float fz = 4.0f + (float)lane;
      float p0 = fx - sPT[0], p1 = fy - sPT[1], p2 = fz - sPT[2];
      float q0 = (sP[0]*p0 + sP[1]*p1) + sP[2]*p2;
      float q1 = (sP[3]*p0 + sP[4]*p1) + sP[5]*p2;
      float q2 = (sP[6]*p0 + sP[7]*p1) + sP[8]*p2;
      float r0 = q0*q2, r1 = q1*q2, r2 = q2;
      float g0 = ((sM[0]*r0 + sM[1]*r1) + sM[2]*r2) + sTR[0];
      float g1 = ((sM[3]*r0 + sM[4]*r1) + sM[5]*r2) + sTR[1];
      float g2 = ((sM[6]*r0 + sM[7]*r1) + sM[8]*r2) + sTR[2];
      int ix = (int)((g0 + 50.0f) / 0.5f);
      int iy = (int)((g1 + 50.0f) / 0.5f);
      int iz = (int)((g2 + 10.0f) / 20.0f);
      bool kept = (ix >= 0) & (ix < NXX) & (iy >= 0) & (iy < NXY) & (iz == 0);
      int v = ix*NXY + iy;
      sVox[h][lane] = kept ? v : -1;
      sDep[h][lane] = e / s;
      if (kept) {
        int t = v >> 6;
        atomicOr(&sMask[t >> 5], 1u << (t & 31));   // LDS dedup
      }
    }
  }
  __syncthreads();

  // records: rec[(col*41 + d)*8 + h], coalesced 8B writes (e = d*8+h)
  int2* __restrict__ rc = recs + (size_t)col*DNUM*FH;
  for (int e = tid; e < DNUM*FH; e += 512) {
    int d = e >> 3, h = e & 7;
    rc[e] = make_int2(sVox[h][d], __float_as_int(sDep[h][d]));
  }
  // publish dirty bitmap (<=20 global atomicOr per block)
  if (tid < MWPB && sMask[tid])
    atomicOr(&dirty[b*MWPB + tid], sMask[tid]);
}

// Zero ONLY dirty tiles of scratch (16 KB each), XCD-pinned (id&7 = b).
// Clean tiles are never read downstream, so they may hold stale data.
__global__ __launch_bounds__(256) void lss_zero_dirty(const unsigned* __restrict__ dirty,
                                                      float4* __restrict__ ws4) {
  const int id = blockIdx.x;
  const int b  = id & 7;
  const int t  = id >> 3;                          // tile 0..624
  if (!((dirty[b*MWPB + (t >> 5)] >> (t & 31)) & 1u)) return;
  const float4 z = make_float4(0.f, 0.f, 0.f, 0.f);
  float4* p = ws4 + (size_t)b*(OUT_PER_B/4) + (size_t)t*1024 + threadIdx.x;
  p[0] = z; p[256] = z; p[512] = z; p[768] = z;
}

// Phase 2: pure atomic kernel. One wave per (col,d) task; 4 waves/block;
// grid = 1353*8, XCD-pinned (blk&7 = b). Register-only h-merge, then
// coalesced merged atomics (64 lanes -> 4 cache lines, XCD-local).
__global__ __launch_bounds__(256) void lss_atomic(const int2* __restrict__ recs,
                                                  const float* __restrict__ featT,
                                                  float* __restrict__ dst) {
  const int blk  = blockIdx.x;
  const int b    = blk & 7;
  const int q    = blk >> 3;          // 0..1352
  const int wv   = (threadIdx.x >> 6);
  const int lane = threadIdx.x & 63;
  const int task = q*4 + wv;          // 0..5411
  const int j    = task / DNUM;
  const int d    = task - j*DNUM;
  const int col  = b*NCPB + j;

  const int2* __restrict__ r8 = recs + ((size_t)col*DNUM + d)*FH;
  int   vox[FH];
  float dep[FH];
  #pragma unroll
  for (int h = 0; h < FH; h++) {
    int2 e = r8[h];
    vox[h] = e.x;
    dep[h] = __int_as_float(e.y);
  }

  float f[FH];
  const float* __restrict__ ft = featT + (size_t)col*FH*CAMC + lane;
  #pragma unroll
  for (int h = 0; h < FH; h++) f[h] = ft[h*CAMC];

  float* __restrict__ sb = dst + (size_t)b*OUT_PER_B + lane;
  unsigned done = 0;
  #pragma unroll
  for (int h = 0; h < FH; h++) {
    if ((done >> h) & 1u) continue;
    int v = vox[h];                   // register, wave-uniform
    if (v < 0) continue;
    float wsum = dep[h] * f[h];
    #pragma unroll
    for (int h2 = h + 1; h2 < FH; h2++) {
      if (vox[h2] == v) {
        wsum += dep[h2] * f[h2];
        done |= 1u << h2;
      }
    }
    atomicAdd(sb + (size_t)v*CAMC, wsum);
  }
}

// (B, XY, C) -> (B, C, XY) tiled transpose, XCD-pinned by batch.
// Clean tiles (dirty bit unset) write zeros directly — no scratch read.
__global__ __launch_bounds__(256) void lss_transpose(const float* __restrict__ src,
                                                     const unsigned* __restrict__ dirty,
                                                     float* __restrict__ out) {
  __shared__ float tile[64][65];
  const int id = blockIdx.x;
  const int b  = id & 7;
  const int t  = id >> 3;                         // tile 0..624
  const int v0 = t * 64;
  const int tx = threadIdx.x & 63;
  const int ty = threadIdx.x >> 6;                // 0..3
  float* dstp = out + (size_t)b*OUT_PER_B + v0;

  const bool isDirty = (dirty[b*MWPB + (t >> 5)] >> (t & 31)) & 1u;
  if (!isDirty) {
    #pragma unroll
    for (int r = ty; r < 64; r += 4)
      dstp[(size_t)r*KVOX + tx] = 0.0f;           // coalesced zero-fill
    return;
  }

  const float* s = src + ((size_t)b*KVOX + v0) * CAMC;
  #pragma unroll
  for (int r = ty; r < 64; r += 4)
    tile[r][tx] = s[r*CAMC + tx];                 // coalesced
  __syncthreads();
  #pragma unroll
  for (int r = ty; r < 64; r += 4)
    dstp[(size_t)r*KVOX + tx] = tile[tx][r];      // coalesced, bank-conflict-free
}

// ---------------- fallback (tiny ws): round-1 direct atomic path ----------------
__global__ void lss_prep(const float* __restrict__ rots,
                         const float* __restrict__ intrins,
                         const float* __restrict__ post_rots,
                         float* __restrict__ prep) {
  #pragma clang fp contract(off)
  int bn = threadIdx.x;
  if (bn >= BN) return;
  float P[9], IC[9];
  inv3x3(post_rots + bn*9, P);
  inv3x3(intrins + bn*9, IC);
  const float* R = rots + bn*9;
  float* o = prep + bn*18;
  #pragma unroll
  for (int q = 0; q < 9; q++) o[q] = P[q];
  #pragma unroll
  for (int r = 0; r < 3; r++)
    #pragma unroll
    for (int k = 0; k < 3; k++)
      o[9 + r*3 + k] = (R[r*3+0]*IC[0+k] + R[r*3+1]*IC[3+k]) + R[r*3+2]*IC[6+k];
}

__global__ __launch_bounds__(64) void lss_scatter_direct(const float* __restrict__ cam_out,
                                                         const float* __restrict__ trans,
                                                         const float* __restrict__ post_trans,
                                                         const float* __restrict__ prep,
                                                         float* __restrict__ out) {
  #pragma clang fp contract(off)
  const int blk = blockIdx.x;
  const int bn  = blk / HW;
  const int pix = blk % HW;
  const int h   = pix / FW;
  const int w   = pix % FW;
  const int b   = bn / NCAM;
  const int tid = threadIdx.x;
  __shared__ float sP[9], sM[9], sPT[3], sTR[3];
  __shared__ float sDepth[DNUM];
  __shared__ int   sVoff[DNUM];
  if (tid < 9)       sP[tid]      = prep[bn*18 + tid];
  else if (tid < 18) sM[tid-9]    = prep[bn*18 + tid];
  else if (tid < 21) sPT[tid-18]  = post_trans[bn*3 + (tid-18)];
  else if (tid < 24) sTR[tid-21]  = trans[bn*3 + (tid-21)];
  __syncthreads();
  const int base = bn*CAM_STRIDE + h*FW + w;
  float logit = (tid < DNUM) ? cam_out[base + tid*HW] : -INFINITY;
  float mx = logit;
  #pragma unroll
  for (int off = 32; off >= 1; off >>= 1) mx = fmaxf(mx, __shfl_xor(mx, off, 64));
  float e = expf(logit - mx);
  float s = e;
  #pragma unroll
  for (int off = 32; off >= 1; off >>= 1) s += __shfl_xor(s, off, 64);
  float depth = e / s;
  if (tid < DNUM) {
    float fx = (float)((double)w * (351.0 / 21.0));
    float fy = (float)((double)h * (127.0 / 7.0));
    float fz = 4.0f + (float)tid;
    float p0 = fx - sPT[0], p1 = fy - sPT[1], p2 = fz - sPT[2];
    float q0 = (sP[0]*p0 + sP[1]*p1) + sP[2]*p2;
    float q1 = (sP[3]*p0 + sP[4]*p1) + sP[5]*p2;
    float q2 = (sP[6]*p0 + sP[7]*p1) + sP[8]*p2;
    float r0 = q0*q2, r1 = q1*q2, r2 = q2;
    float g0 = ((sM[0]*r0 + sM[1]*r1) + sM[2]*r2) + sTR[0];
    float g1 = ((sM[3]*r0 + sM[4]*r1) + sM[5]*r2) + sTR[1];
    float g2 = ((sM[6]*r0 + sM[7]*r1) + sM[8]*r2) + sTR[2];
    int ix = (int)((g0 + 50.0f) / 0.5f);
    int iy = (int)((g1 + 50.0f) / 0.5f);
    int iz = (int)((g2 + 10.0f) / 20.0f);
    bool kept = (ix >= 0) & (ix < NXX) & (iy >= 0) & (iy < NXY) & (iz == 0);
    sVoff[tid]  = kept ? (ix*NXY + iy) : -1;
    sDepth[tid] = depth;
  }
  __syncthreads();
  const float feat = cam_out[base + (DNUM + tid)*HW];
  float* outb = out + (size_t)b*OUT_PER_B + (size_t)tid*KVOX;
  #pragma unroll 1
  for (int d = 0; d < DNUM; d++) {
    int v = sVoff[d];
    if (v >= 0) atomicAdd(outb + v, sDepth[d] * feat);
  }
}

extern "C" void kernel_launch(void* const* d_in, const int* in_sizes, int n_in,
                              void* d_out, int out_size, void* d_ws, size_t ws_size,
                              hipStream_t stream) {
  const float* cam_out    = (const float*)d_in[0];
  const float* rots       = (const float*)d_in[1];
  const float* trans      = (const float*)d_in[2];
  const float* intrins    = (const float*)d_in[3];
  const float* post_rots  = (const float*)d_in[4];
  const float* post_trans = (const float*)d_in[5];
  float* out = (float*)d_out;
  char*  ws  = (char*)d_ws;

  // ws layout: scratch (82 MB) | featT (2.2 MB) | recs (2.8 MB) | dirty (640 B)
  float*    scratch = (float*)ws;
  float*    featT   = scratch + SCRATCH_FLOATS;              // PIXT*CAMC floats
  int2*     recs    = (int2*)(featT + (size_t)PIXT*CAMC);    // NPTS int2 (8B-aligned)
  unsigned* dirty   = (unsigned*)(recs + NPTS);              // MWORDS
  const size_t need = SCRATCH_FLOATS*4 + (size_t)PIXT*CAMC*4 + (size_t)NPTS*8
                      + MWORDS*4;

  if (ws_size >= need) {
    hipMemsetAsync(dirty, 0, MWORDS*sizeof(unsigned), stream);
    lss_geom<<<NCOL, 512, 0, stream>>>(cam_out, rots, trans, intrins,
                                       post_rots, post_trans, featT, recs, dirty);
    lss_zero_dirty<<<5000, 256, 0, stream>>>(dirty, (float4*)scratch);
    lss_atomic<<<ATOM_BLKS_PB * 8, 256, 0, stream>>>(recs, featT, scratch);
    lss_transpose<<<5000, 256, 0, stream>>>(scratch, dirty, out);
  } else {
    float* prep = (float*)ws;   // BN*18 floats
    hipMemsetAsync(out, 0, (size_t)out_size * sizeof(float), stream);
    lss_prep<<<1, 64, 0, stream>>>(rots, intrins, post_rots, prep);
    lss_scatter_direct<<<BN * HW, 64, 0, stream>>>(cam_out, trans, post_trans, prep, out);
  }
}